// Round 2
// baseline (1471.839 us; speedup 1.0000x reference)
//
#include <hip/hip_runtime.h>
#include <math.h>

#define B_ 4
#define S_ 16
#define N_ 32
#define C_ 512
#define D_ 10
#define DD_ 100
#define ATT_IN_ 312
#define ATT_H_ 512
#define ATT_DIM_ 514
#define CX_ 514

// ---------------- K1: a = relu(att @ attW1 + attb1)   (128 x 512, K=312)
__global__ void k_att1(const float* __restrict__ att, const float* __restrict__ W1,
                       const float* __restrict__ b1, float* __restrict__ a_out) {
    __shared__ float row[ATT_IN_];
    int r = blockIdx.x;            // 0..127  (b*32+n)
    int tid = threadIdx.x;         // 256 threads
    for (int k = tid; k < ATT_IN_; k += 256) row[k] = att[r * ATT_IN_ + k];
    __syncthreads();
    float acc0 = b1[tid], acc1 = b1[tid + 256];
#pragma unroll 4
    for (int k = 0; k < ATT_IN_; k++) {
        float v = row[k];
        acc0 = fmaf(v, W1[k * 512 + tid], acc0);
        acc1 = fmaf(v, W1[k * 512 + tid + 256], acc1);
    }
    a_out[r * 512 + tid] = fmaxf(acc0, 0.f);
    a_out[r * 512 + tid + 256] = fmaxf(acc1, 0.f);
}

// ---------------- K2+K3 fused: att_f = relu(a @ attW2 + attb2); ha = att_f @ gW1[514:]
__global__ void k_att2(const float* __restrict__ a_in, const float* __restrict__ W2,
                       const float* __restrict__ b2, const float* __restrict__ gW1,
                       float* __restrict__ ha) {
    __shared__ float arow[512];
    __shared__ float frow[ATT_DIM_];
    int r = blockIdx.x;            // 0..127
    int tid = threadIdx.x;         // 256 threads
    for (int k = tid; k < 512; k += 256) arow[k] = a_in[r * 512 + k];
    __syncthreads();
    for (int o = tid; o < ATT_DIM_; o += 256) {
        float acc = b2[o];
#pragma unroll 4
        for (int k = 0; k < 512; k++) acc = fmaf(arow[k], W2[k * ATT_DIM_ + o], acc);
        frow[o] = fmaxf(acc, 0.f);
    }
    __syncthreads();
    {
        int o = tid;               // 256 outputs, no bias here (gb1 added later)
        float acc = 0.f;
#pragma unroll 4
        for (int k = 0; k < ATT_DIM_; k++) acc = fmaf(frow[k], gW1[(CX_ + k) * 256 + o], acc);
        ha[r * 256 + o] = acc;
    }
}

// ---------------- K4: hx[bs][p][c] = sum_k xc[bs,p,k] * gW1[k][c]  (K=514 incl. coords)
__global__ __launch_bounds__(512) void k_hx(const float* __restrict__ x_f,
                                            const float* __restrict__ gW1,
                                            float* __restrict__ hx) {
    __shared__ float At[32 * 128];     // [k_local][p], p padded to 128
    int bs = blockIdx.x >> 2, cb = blockIdx.x & 3;   // 64 (b,s) x 4 column chunks of 64
    int tid = threadIdx.x;
    int colg = tid & 15, rowg = tid >> 4;            // colg: 16x4 cols, rowg: 32x4 rows
    int cbase = cb * 64 + colg * 4;
    float acc[4][4] = {};
    const float* xb = x_f + (size_t)bs * C_ * DD_;
    int cl = tid >> 4;             // staging: channel-local 0..31
    int p0 = (tid & 15) * 8;       // staging: p start 0..120
    for (int kt = 0; kt < 16; kt++) {
        __syncthreads();
        {   // stage A-tile transposed: At[cl][p0..p0+8)
            int c = kt * 32 + cl;
            float4 v0 = make_float4(0, 0, 0, 0), v1 = make_float4(0, 0, 0, 0);
            if (p0 + 4 <= DD_) v0 = *(const float4*)&xb[c * DD_ + p0];
            if (p0 + 8 <= DD_) v1 = *(const float4*)&xb[c * DD_ + p0 + 4];
            *(float4*)&At[cl * 128 + p0] = v0;
            *(float4*)&At[cl * 128 + p0 + 4] = v1;
        }
        __syncthreads();
#pragma unroll 4
        for (int k2 = 0; k2 < 32; k2++) {
            float4 w = *(const float4*)&gW1[(kt * 32 + k2) * 256 + cbase];
            float4 a = *(const float4*)&At[k2 * 128 + rowg * 4];
            float av[4] = {a.x, a.y, a.z, a.w};
            float wv[4] = {w.x, w.y, w.z, w.w};
#pragma unroll
            for (int i = 0; i < 4; i++)
#pragma unroll
                for (int j = 0; j < 4; j++) acc[i][j] = fmaf(av[i], wv[j], acc[i][j]);
        }
    }
    // coord channels 512/513 + store
    float4 w512 = *(const float4*)&gW1[512 * 256 + cbase];
    float4 w513 = *(const float4*)&gW1[513 * 256 + cbase];
    float wa[4] = {w512.x, w512.y, w512.z, w512.w};
    float wb[4] = {w513.x, w513.y, w513.z, w513.w};
#pragma unroll
    for (int i = 0; i < 4; i++) {
        int p = rowg * 4 + i;
        if (p < DD_) {
            float ci = (float)(p / 10) * 0.1f;
            float cj = (float)(p % 10) * 0.1f;
            float ov[4];
#pragma unroll
            for (int j = 0; j < 4; j++) ov[j] = acc[i][j] + ci * wa[j] + cj * wb[j];
            *(float4*)&hx[((size_t)bs * DD_ + p) * 256 + cbase] =
                make_float4(ov[0], ov[1], ov[2], ov[3]);
        }
    }
}

// ---------------- Main: h0 = relu(hx+ha+gb1) -> 3 fused 256x256 layers -> sum over p
// grid: 64 (b,s) x 50 row-blocks of 64 rows; 512 threads; A-tile 64KB LDS (k-major)
// A layout: physical row = row ^ (k & 60)  (XOR swizzle).
//   Reads in the k-loop are wave-uniform broadcasts -> conflict-free under any
//   per-k row bijection; swizzle keeps float4 contiguity (h has no bits <2) and
//   cuts the per-lane scattered writeback from a 64-way to an 8-way conflict
//   (bank sees only row bits 0-4, bits 0-1 reserved for float4 => 8 is the floor).
#define AROW(k, r) ((k) * 64 + ((r) ^ ((k) & 60)))
__global__ __launch_bounds__(512, 4) void k_main(
    const float* __restrict__ hx, const float* __restrict__ ha,
    const float* __restrict__ gb1, const float* __restrict__ gW2,
    const float* __restrict__ gb2, const float* __restrict__ gW3,
    const float* __restrict__ gb3, const float* __restrict__ gW4,
    const float* __restrict__ gb4, float* __restrict__ hsum) {
    __shared__ float A[256 * 64];      // [k][row'], 64 KB
    int bs = blockIdx.x / 50, blk = blockIdx.x % 50;
    int R0 = blk * 64;                 // row base within this (b,s)'s 3200 rows
    int b = bs >> 4;                   // S_=16
    int tid = threadIdx.x;
    int colg = tid & 63, rowg = tid >> 6;   // 64 col-groups x 4, 8 row-groups x 8

    // stage h0 = relu(hx + ha + gb1), transposed+swizzled into A
    {
        int i = tid >> 3, c0 = (tid & 7) * 32;
        int rl = R0 + i;
        int n = rl / 100, p = rl % 100;
        const float* hxr = hx + ((size_t)bs * DD_ + p) * 256;
        const float* har = ha + (size_t)(b * N_ + n) * 256;
#pragma unroll 4
        for (int cc = 0; cc < 32; cc++) {
            int c = c0 + cc;
            A[AROW(c, i)] = fmaxf(hxr[c] + har[c] + gb1[c], 0.f);
        }
    }
    __syncthreads();

    const float* Ws[3] = {gW2, gW3, gW4};
    const float* Bs[3] = {gb2, gb3, gb4};
    float acc[8][4];
#pragma unroll
    for (int layer = 0; layer < 3; layer++) {
        const float* W = Ws[layer] + colg * 4;
#pragma unroll
        for (int i = 0; i < 8; i++)
#pragma unroll
            for (int j = 0; j < 4; j++) acc[i][j] = 0.f;
#pragma unroll 2
        for (int k = 0; k < 256; k++) {
            int h = k & 60;
            float4 w = *(const float4*)&W[k * 256];
            float4 a0 = *(const float4*)&A[k * 64 + ((rowg * 8) ^ h)];
            float4 a1 = *(const float4*)&A[k * 64 + ((rowg * 8 + 4) ^ h)];
            float av[8] = {a0.x, a0.y, a0.z, a0.w, a1.x, a1.y, a1.z, a1.w};
            float wv[4] = {w.x, w.y, w.z, w.w};
#pragma unroll
            for (int i = 0; i < 8; i++)
#pragma unroll
                for (int j = 0; j < 4; j++) acc[i][j] = fmaf(av[i], wv[j], acc[i][j]);
        }
        float4 bias = *(const float4*)&Bs[layer][colg * 4];
        float bv[4] = {bias.x, bias.y, bias.z, bias.w};
        __syncthreads();   // everyone done reading A before overwrite
        if (layer < 2) {
#pragma unroll
            for (int j = 0; j < 4; j++) {
                int c = colg * 4 + j;
#pragma unroll
                for (int i = 0; i < 8; i++)
                    A[AROW(c, rowg * 8 + i)] = fmaxf(acc[i][j] + bv[j], 0.f);
            }
            __syncthreads();
        } else {
            // relu + partial sum over rows, split by n-segment (static indexing only)
            int n0 = R0 / 100;
            int bound = (n0 + 1) * 100;
            float part0[4] = {}, part1[4] = {};
#pragma unroll
            for (int i = 0; i < 8; i++) {
                int rl = R0 + rowg * 8 + i;
                bool in1 = (rl >= bound);
#pragma unroll
                for (int j = 0; j < 4; j++) {
                    float v = fmaxf(acc[i][j] + bv[j], 0.f);
                    part0[j] += in1 ? 0.f : v;
                    part1[j] += in1 ? v : 0.f;
                }
            }
            // P[seg][rowg][c] in reused LDS (plain layout, tiny phase)
#pragma unroll
            for (int j = 0; j < 4; j++) {
                A[(0 * 8 + rowg) * 256 + colg * 4 + j] = part0[j];
                A[(1 * 8 + rowg) * 256 + colg * 4 + j] = part1[j];
            }
            __syncthreads();
            int seg = tid >> 8, c = tid & 255;
            float v = 0.f;
#pragma unroll
            for (int g = 0; g < 8; g++) v += A[(seg * 8 + g) * 256 + c];
            int n_last = (R0 + 63) / 100;
            int nt = n0 + seg;
            if (nt <= n_last) atomicAdd(&hsum[((size_t)bs * N_ + nt) * 256 + c], v);
        }
    }
}

// ---------------- Head: hsum -> f1 -> f2 -> y(29) -> BN -> relu -> score -> loss
__global__ void k_head(const float* __restrict__ hsum,
                       const float* __restrict__ fW1, const float* __restrict__ fb1,
                       const float* __restrict__ fW2, const float* __restrict__ fb2,
                       const float* __restrict__ fW3, const float* __restrict__ fb3,
                       const float* __restrict__ bn_gamma, const float* __restrict__ bn_beta,
                       const float* __restrict__ bn_mean, const float* __restrict__ bn_var,
                       const float* __restrict__ fW4, const float* __restrict__ fb4,
                       const int* __restrict__ x_label, const int* __restrict__ att_label,
                       float* __restrict__ out) {
    __shared__ float H[8 * 256];
    __shared__ float Y[8 * 29];
    __shared__ float partial[8];
    int RB = blockIdx.x * 8;       // 256 blocks x 8 rows of (b,s,n)
    int tid = threadIdx.x;         // 256 threads
    {
        int r = tid >> 5, c0 = (tid & 31) * 8;
#pragma unroll
        for (int cc = 0; cc < 8; cc++)
            H[r * 256 + c0 + cc] = hsum[(size_t)(RB + r) * 256 + c0 + cc];
    }
    __syncthreads();
    const float* Ws[2] = {fW1, fW2};
    const float* Bs[2] = {fb1, fb2};
#pragma unroll
    for (int layer = 0; layer < 2; layer++) {
        float acc[8];
#pragma unroll
        for (int r = 0; r < 8; r++) acc[r] = Bs[layer][tid];
        const float* W = Ws[layer];
#pragma unroll 4
        for (int k = 0; k < 256; k++) {
            float w = W[k * 256 + tid];
#pragma unroll
            for (int r = 0; r < 8; r++) acc[r] = fmaf(H[r * 256 + k], w, acc[r]);
        }
        __syncthreads();
#pragma unroll
        for (int r = 0; r < 8; r++) H[r * 256 + tid] = fmaxf(acc[r], 0.f);
        __syncthreads();
    }
    if (tid < 8 * 29) {
        int r = tid / 29, c = tid % 29;
        float acc = fb3[c];
#pragma unroll 4
        for (int k = 0; k < 256; k++) acc = fmaf(H[r * 256 + k], fW3[k * 29 + c], acc);
        float v = (acc - bn_mean[c]) * rsqrtf(bn_var[c] + 1e-5f) * bn_gamma[c] + bn_beta[c];
        Y[r * 29 + c] = fmaxf(v, 0.f);
    }
    __syncthreads();
    if (tid < 8) {
        int r = tid;
        float s = fb4[0];
#pragma unroll
        for (int c = 0; c < 29; c++) s = fmaf(Y[r * 29 + c], fW4[c], s);
        float score = 1.f / (1.f + expf(-s));
        int g = RB + r;
        int b = g >> 9;            // S*N = 512
        int rem = g & 511;
        int si = rem >> 5, n = rem & 31;
        float label = (x_label[b * S_ + si] == att_label[b * N_ + n]) ? 1.f : 0.f;
        float d = label - score;
        partial[r] = d * d;
    }
    __syncthreads();
    if (tid == 0) {
        float s = 0.f;
#pragma unroll
        for (int r = 0; r < 8; r++) s += partial[r];
        atomicAdd(out, s);
    }
}

extern "C" void kernel_launch(void* const* d_in, const int* in_sizes, int n_in,
                              void* d_out, int out_size, void* d_ws, size_t ws_size,
                              hipStream_t stream) {
    const float* x_f      = (const float*)d_in[0];
    const float* att      = (const float*)d_in[1];
    const int*   x_label  = (const int*)d_in[2];
    const int*   att_label= (const int*)d_in[3];
    const float* attW1    = (const float*)d_in[4];
    const float* attb1    = (const float*)d_in[5];
    const float* attW2    = (const float*)d_in[6];
    const float* attb2    = (const float*)d_in[7];
    const float* gW1      = (const float*)d_in[8];
    const float* gb1      = (const float*)d_in[9];
    const float* gW2      = (const float*)d_in[10];
    const float* gb2      = (const float*)d_in[11];
    const float* gW3      = (const float*)d_in[12];
    const float* gb3      = (const float*)d_in[13];
    const float* gW4      = (const float*)d_in[14];
    const float* gb4      = (const float*)d_in[15];
    const float* fW1      = (const float*)d_in[16];
    const float* fb1      = (const float*)d_in[17];
    const float* fW2      = (const float*)d_in[18];
    const float* fb2      = (const float*)d_in[19];
    const float* fW3      = (const float*)d_in[20];
    const float* fb3      = (const float*)d_in[21];
    const float* bn_gamma = (const float*)d_in[22];
    const float* bn_beta  = (const float*)d_in[23];
    const float* bn_mean  = (const float*)d_in[24];
    const float* bn_var   = (const float*)d_in[25];
    const float* fW4      = (const float*)d_in[26];
    const float* fb4      = (const float*)d_in[27];

    float* ws   = (float*)d_ws;
    float* a_buf = ws;                    // 128*512   = 65536
    float* ha    = ws + 65536;            // 128*256   = 32768
    float* hx    = ws + 98304;            // 64*100*256= 1638400
    float* hsum  = ws + 1736704;          // 2048*256  = 524288  (total ~9.05 MB)

    hipMemsetAsync(d_out, 0, sizeof(float), stream);
    hipMemsetAsync(hsum, 0, (size_t)2048 * 256 * sizeof(float), stream);

    k_att1<<<128, 256, 0, stream>>>(att, attW1, attb1, a_buf);
    k_att2<<<128, 256, 0, stream>>>(a_buf, attW2, attb2, gW1, ha);
    k_hx<<<256, 512, 0, stream>>>(x_f, gW1, hx);
    k_main<<<3200, 512, 0, stream>>>(hx, ha, gb1, gW2, gb2, gW3, gb3, gW4, gb4, hsum);
    k_head<<<256, 256, 0, stream>>>(hsum, fW1, fb1, fW2, fb2, fW3, fb3,
                                    bn_gamma, bn_beta, bn_mean, bn_var,
                                    fW4, fb4, x_label, att_label, (float*)d_out);
}

// Round 3
// 762.214 us; speedup vs baseline: 1.9310x; 1.9310x over previous
//
#include <hip/hip_runtime.h>
#include <math.h>

#define B_ 4
#define S_ 16
#define N_ 32
#define C_ 512
#define D_ 10
#define DD_ 100
#define ATT_IN_ 312
#define ATT_H_ 512
#define ATT_DIM_ 514
#define CX_ 514

typedef __attribute__((ext_vector_type(8))) short short8;
typedef __attribute__((ext_vector_type(4))) float floatx4;
typedef __attribute__((ext_vector_type(4))) unsigned int uintx4;

// Split fp32 v into bf16 hi + bf16 lo, packed u32 = hi | lo<<16.
// hi = RNE-ish bf16 (round-half-up on bit15); lo = bf16(v - hi) (exact sub).
__device__ __forceinline__ unsigned int pack_hilo(float v) {
    unsigned int vb = __float_as_uint(v);
    unsigned int hib = (vb + 0x8000u) & 0xFFFF0000u;
    float lo = v - __uint_as_float(hib);
    unsigned int lob = __float_as_uint(lo);
    return (hib >> 16) | (((lob + 0x8000u) >> 16) << 16);
}

// ---------------- K1: a = relu(att @ attW1 + attb1)   (128 x 512, K=312)
__global__ void k_att1(const float* __restrict__ att, const float* __restrict__ W1,
                       const float* __restrict__ b1, float* __restrict__ a_out) {
    __shared__ float row[ATT_IN_];
    int r = blockIdx.x;
    int tid = threadIdx.x;
    for (int k = tid; k < ATT_IN_; k += 256) row[k] = att[r * ATT_IN_ + k];
    __syncthreads();
    float acc0 = b1[tid], acc1 = b1[tid + 256];
#pragma unroll 4
    for (int k = 0; k < ATT_IN_; k++) {
        float v = row[k];
        acc0 = fmaf(v, W1[k * 512 + tid], acc0);
        acc1 = fmaf(v, W1[k * 512 + tid + 256], acc1);
    }
    a_out[r * 512 + tid] = fmaxf(acc0, 0.f);
    a_out[r * 512 + tid + 256] = fmaxf(acc1, 0.f);
}

// ---------------- K2+K3 fused: att_f = relu(a @ attW2 + attb2); ha = att_f @ gW1[514:]
__global__ void k_att2(const float* __restrict__ a_in, const float* __restrict__ W2,
                       const float* __restrict__ b2, const float* __restrict__ gW1,
                       float* __restrict__ ha) {
    __shared__ float arow[512];
    __shared__ float frow[ATT_DIM_];
    int r = blockIdx.x;
    int tid = threadIdx.x;
    for (int k = tid; k < 512; k += 256) arow[k] = a_in[r * 512 + k];
    __syncthreads();
    for (int o = tid; o < ATT_DIM_; o += 256) {
        float acc = b2[o];
#pragma unroll 4
        for (int k = 0; k < 512; k++) acc = fmaf(arow[k], W2[k * ATT_DIM_ + o], acc);
        frow[o] = fmaxf(acc, 0.f);
    }
    __syncthreads();
    {
        int o = tid;
        float acc = 0.f;
#pragma unroll 4
        for (int k = 0; k < ATT_DIM_; k++) acc = fmaf(frow[k], gW1[(CX_ + k) * 256 + o], acc);
        ha[r * 256 + o] = acc;
    }
}

// ---------------- K4: hx[bs][p][c] = sum_k xc[bs,p,k] * gW1[k][c]
__global__ __launch_bounds__(512) void k_hx(const float* __restrict__ x_f,
                                            const float* __restrict__ gW1,
                                            float* __restrict__ hx) {
    __shared__ float At[32 * 128];
    int bs = blockIdx.x >> 2, cb = blockIdx.x & 3;
    int tid = threadIdx.x;
    int colg = tid & 15, rowg = tid >> 4;
    int cbase = cb * 64 + colg * 4;
    float acc[4][4] = {};
    const float* xb = x_f + (size_t)bs * C_ * DD_;
    int cl = tid >> 4;
    int p0 = (tid & 15) * 8;
    for (int kt = 0; kt < 16; kt++) {
        __syncthreads();
        {
            int c = kt * 32 + cl;
            float4 v0 = make_float4(0, 0, 0, 0), v1 = make_float4(0, 0, 0, 0);
            if (p0 + 4 <= DD_) v0 = *(const float4*)&xb[c * DD_ + p0];
            if (p0 + 8 <= DD_) v1 = *(const float4*)&xb[c * DD_ + p0 + 4];
            *(float4*)&At[cl * 128 + p0] = v0;
            *(float4*)&At[cl * 128 + p0 + 4] = v1;
        }
        __syncthreads();
#pragma unroll 4
        for (int k2 = 0; k2 < 32; k2++) {
            float4 w = *(const float4*)&gW1[(kt * 32 + k2) * 256 + cbase];
            float4 a = *(const float4*)&At[k2 * 128 + rowg * 4];
            float av[4] = {a.x, a.y, a.z, a.w};
            float wv[4] = {w.x, w.y, w.z, w.w};
#pragma unroll
            for (int i = 0; i < 4; i++)
#pragma unroll
                for (int j = 0; j < 4; j++) acc[i][j] = fmaf(av[i], wv[j], acc[i][j]);
        }
    }
    float4 w512 = *(const float4*)&gW1[512 * 256 + cbase];
    float4 w513 = *(const float4*)&gW1[513 * 256 + cbase];
    float wa[4] = {w512.x, w512.y, w512.z, w512.w};
    float wb[4] = {w513.x, w513.y, w513.z, w513.w};
#pragma unroll
    for (int i = 0; i < 4; i++) {
        int p = rowg * 4 + i;
        if (p < DD_) {
            float ci = (float)(p / 10) * 0.1f;
            float cj = (float)(p % 10) * 0.1f;
            float ov[4];
#pragma unroll
            for (int j = 0; j < 4; j++) ov[j] = acc[i][j] + ci * wa[j] + cj * wb[j];
            *(float4*)&hx[((size_t)bs * DD_ + p) * 256 + cbase] =
                make_float4(ov[0], ov[1], ov[2], ov[3]);
        }
    }
}

// ---------------- W prep: split gW2/3/4 into bf16 hi/lo in MFMA-fragment-linear layout.
// Frag element (L, ks, ct, lane, j): k = ks*32 + (lane>>4)*8 + j, col = ct*16 + (lane&15).
__global__ void k_wprep(const float* __restrict__ gW2, const float* __restrict__ gW3,
                        const float* __restrict__ gW4,
                        unsigned short* __restrict__ Whi, unsigned short* __restrict__ Wlo) {
    int f = blockIdx.x * 256 + threadIdx.x;        // 3 * 65536
    int j = f & 7, lane = (f >> 3) & 63, ct = (f >> 9) & 15, ks = (f >> 13) & 7, L = f >> 16;
    const float* W = (L == 0) ? gW2 : (L == 1) ? gW3 : gW4;
    int k = ks * 32 + ((lane >> 4) << 3) + j;
    int col = ct * 16 + (lane & 15);
    float v = W[k * 256 + col];
    unsigned int vb = __float_as_uint(v);
    unsigned int hib = (vb + 0x8000u) & 0xFFFF0000u;
    float lo = v - __uint_as_float(hib);
    unsigned int lob = __float_as_uint(lo);
    Whi[f] = (unsigned short)(hib >> 16);
    Wlo[f] = (unsigned short)((lob + 0x8000u) >> 16);
}

// ---------------- Main (MFMA): h0=relu(hx+ha+gb1) -> 3 split-bf16 256x256 layers -> p-sum
// Block: 64 rows x 256 cols, 256 thr = 4 waves (2x2), wave-tile 32x128.
// A in LDS: 32 regions (ks 0..7 x rt 0..3), each 64 lanes x 8 u32 (hi|lo<<16),
// slot-swizzled sigma(s) = s ^ ((s>>3)&7): b128 frag reads at the 8-cyc floor,
// per-lane b32 writeback lands 2 lanes/bank (free, m136).
__global__ __launch_bounds__(256, 2) void k_main(
    const float* __restrict__ hx, const float* __restrict__ ha,
    const float* __restrict__ gb1,
    const unsigned short* __restrict__ Whi, const unsigned short* __restrict__ Wlo,
    const float* __restrict__ gb2, const float* __restrict__ gb3,
    const float* __restrict__ gb4, float* __restrict__ hsum) {
    __shared__ unsigned int As[16384];             // 64 KB
    int bs = blockIdx.x / 50, blk = blockIdx.x % 50;
    int R0 = blk * 64;
    int b = bs >> 4;
    int tid = threadIdx.x;
    int l = tid & 63;
    int wid = tid >> 6;
    int wr = wid >> 1, wc = wid & 1;               // rows wr*32.., cols wc*128..

    // ---- stage h0 = relu(hx + ha + gb1) into frag-layout LDS ----
    {
        int i = tid >> 2, q4 = tid & 3;            // row i, k-quarter q4
        int rl = R0 + i;
        int n = rl / 100, p = rl - n * 100;
        const float4* xr = (const float4*)(hx + ((size_t)bs * DD_ + p) * 256 + q4 * 64);
        const float4* ar = (const float4*)(ha + (size_t)(b * N_ + n) * 256 + q4 * 64);
        const float4* br = (const float4*)(gb1 + q4 * 64);
        int rt = i >> 4;
        int la_lo = i & 15;
#pragma unroll
        for (int c4 = 0; c4 < 16; c4++) {
            float4 x = xr[c4], a = ar[c4], bb = br[c4];
            uintx4 u;
            u.x = pack_hilo(fmaxf(x.x + a.x + bb.x, 0.f));
            u.y = pack_hilo(fmaxf(x.y + a.y + bb.y, 0.f));
            u.z = pack_hilo(fmaxf(x.z + a.z + bb.z, 0.f));
            u.w = pack_hilo(fmaxf(x.w + a.w + bb.w, 0.f));
            int k0 = q4 * 64 + c4 * 4;
            int ks = k0 >> 5;
            int lane_addr = la_lo | (((k0 >> 3) & 3) << 4);
            int slot = lane_addr * 2 + ((k0 >> 2) & 1);
            int sg = slot ^ ((slot >> 3) & 7);
            *(uintx4*)&As[((ks * 4 + rt) << 9) + sg * 4] = u;
        }
    }
    __syncthreads();

    int s0 = (2 * l) ^ ((l >> 2) & 7);             // swizzled slot of j=0..3 (j=4..7 at s0^1)
    int colb = wc * 128 + (l & 15);
    const float* biases[3] = {gb2, gb3, gb4};

    floatx4 acc[2][8];
    for (int layer = 0; layer < 3; layer++) {
#pragma unroll
        for (int ti = 0; ti < 2; ti++)
#pragma unroll
            for (int tj = 0; tj < 8; tj++) acc[ti][tj] = (floatx4){0.f, 0.f, 0.f, 0.f};

        const unsigned short* WhiL = Whi + layer * 65536;
        const unsigned short* WloL = Wlo + layer * 65536;
#pragma unroll 2
        for (int ks = 0; ks < 8; ks++) {
            short8 ahi[2], alo[2];
#pragma unroll
            for (int ti = 0; ti < 2; ti++) {
                int base = (ks * 4 + (wr * 2 + ti)) << 9;
                uintx4 q0 = *(const uintx4*)&As[base + s0 * 4];         // j 0..3
                uintx4 q1 = *(const uintx4*)&As[base + (s0 ^ 1) * 4];   // j 4..7
                uintx4 hh, ll;
                hh.x = __builtin_amdgcn_perm(q0.y, q0.x, 0x05040100u);
                hh.y = __builtin_amdgcn_perm(q0.w, q0.z, 0x05040100u);
                hh.z = __builtin_amdgcn_perm(q1.y, q1.x, 0x05040100u);
                hh.w = __builtin_amdgcn_perm(q1.w, q1.z, 0x05040100u);
                ll.x = __builtin_amdgcn_perm(q0.y, q0.x, 0x07060302u);
                ll.y = __builtin_amdgcn_perm(q0.w, q0.z, 0x07060302u);
                ll.z = __builtin_amdgcn_perm(q1.y, q1.x, 0x07060302u);
                ll.w = __builtin_amdgcn_perm(q1.w, q1.z, 0x07060302u);
                ahi[ti] = __builtin_bit_cast(short8, hh);
                alo[ti] = __builtin_bit_cast(short8, ll);
            }
#pragma unroll
            for (int tj = 0; tj < 8; tj++) {
                int ct = wc * 8 + tj;
                size_t off = (size_t)((ks * 16 + ct) * 64 + l) * 8;
                short8 bhi = *(const short8*)(WhiL + off);
                short8 blo = *(const short8*)(WloL + off);
#pragma unroll
                for (int ti = 0; ti < 2; ti++) {
                    acc[ti][tj] = __builtin_amdgcn_mfma_f32_16x16x32_bf16(ahi[ti], bhi, acc[ti][tj], 0, 0, 0);
                    acc[ti][tj] = __builtin_amdgcn_mfma_f32_16x16x32_bf16(ahi[ti], blo, acc[ti][tj], 0, 0, 0);
                    acc[ti][tj] = __builtin_amdgcn_mfma_f32_16x16x32_bf16(alo[ti], bhi, acc[ti][tj], 0, 0, 0);
                }
            }
        }
        __syncthreads();                            // all reads of As done

        if (layer < 2) {
            const float* bias = biases[layer];
#pragma unroll
            for (int tj = 0; tj < 8; tj++) {
                int col = colb + tj * 16;
                float bv = bias[col];
                int ksp = col >> 5;
                int g2 = (col >> 3) & 3;
                int jj = col & 7;
#pragma unroll
                for (int ti = 0; ti < 2; ti++) {
                    int base = (ksp * 4 + (wr * 2 + ti)) << 9;
#pragma unroll
                    for (int r = 0; r < 4; r++) {
                        float v = fmaxf(acc[ti][tj][r] + bv, 0.f);
                        int lane_addr = ((l >> 4) * 4 + r) | (g2 << 4);
                        int widx = lane_addr * 8 + jj;
                        int slot = widx >> 2;
                        int sg = slot ^ ((slot >> 3) & 7);
                        As[base + sg * 4 + (widx & 3)] = pack_hilo(v);
                    }
                }
            }
            __syncthreads();
        } else {
            // relu + p-sum (rows split over <=2 n-segments), via LDS partial buffer
            float* Pf = (float*)As;
            int n0 = R0 / 100;
            int bound = (n0 + 1) * 100;
            Pf[tid] = 0.f;
            Pf[tid + 256] = 0.f;
            __syncthreads();
            const float* bias = biases[2];
#pragma unroll
            for (int tj = 0; tj < 8; tj++) {
                int col = colb + tj * 16;
                float bv = bias[col];
                float p0 = 0.f, p1 = 0.f;
#pragma unroll
                for (int ti = 0; ti < 2; ti++) {
#pragma unroll
                    for (int r = 0; r < 4; r++) {
                        int rl = R0 + wr * 32 + ti * 16 + (l >> 4) * 4 + r;
                        float v = fmaxf(acc[ti][tj][r] + bv, 0.f);
                        bool in1 = rl >= bound;
                        p0 += in1 ? 0.f : v;
                        p1 += in1 ? v : 0.f;
                    }
                }
                atomicAdd(&Pf[col], p0);
                atomicAdd(&Pf[256 + col], p1);
            }
            __syncthreads();
            {
                int n_last = (R0 + 63) / 100;
                atomicAdd(&hsum[((size_t)bs * N_ + n0) * 256 + tid], Pf[tid]);
                if (n0 + 1 <= n_last)
                    atomicAdd(&hsum[((size_t)bs * N_ + n0 + 1) * 256 + tid], Pf[tid + 256]);
            }
        }
    }
}

// ---------------- Head: hsum -> f1 -> f2 -> y(29) -> BN -> relu -> score -> loss
__global__ void k_head(const float* __restrict__ hsum,
                       const float* __restrict__ fW1, const float* __restrict__ fb1,
                       const float* __restrict__ fW2, const float* __restrict__ fb2,
                       const float* __restrict__ fW3, const float* __restrict__ fb3,
                       const float* __restrict__ bn_gamma, const float* __restrict__ bn_beta,
                       const float* __restrict__ bn_mean, const float* __restrict__ bn_var,
                       const float* __restrict__ fW4, const float* __restrict__ fb4,
                       const int* __restrict__ x_label, const int* __restrict__ att_label,
                       float* __restrict__ out) {
    __shared__ float H[8 * 256];
    __shared__ float Y[8 * 29];
    __shared__ float partial[8];
    int RB = blockIdx.x * 8;
    int tid = threadIdx.x;
    {
        int r = tid >> 5, c0 = (tid & 31) * 8;
#pragma unroll
        for (int cc = 0; cc < 8; cc++)
            H[r * 256 + c0 + cc] = hsum[(size_t)(RB + r) * 256 + c0 + cc];
    }
    __syncthreads();
    const float* Ws[2] = {fW1, fW2};
    const float* Bs[2] = {fb1, fb2};
#pragma unroll
    for (int layer = 0; layer < 2; layer++) {
        float acc[8];
#pragma unroll
        for (int r = 0; r < 8; r++) acc[r] = Bs[layer][tid];
        const float* W = Ws[layer];
#pragma unroll 4
        for (int k = 0; k < 256; k++) {
            float w = W[k * 256 + tid];
#pragma unroll
            for (int r = 0; r < 8; r++) acc[r] = fmaf(H[r * 256 + k], w, acc[r]);
        }
        __syncthreads();
#pragma unroll
        for (int r = 0; r < 8; r++) H[r * 256 + tid] = fmaxf(acc[r], 0.f);
        __syncthreads();
    }
    if (tid < 8 * 29) {
        int r = tid / 29, c = tid % 29;
        float acc = fb3[c];
#pragma unroll 4
        for (int k = 0; k < 256; k++) acc = fmaf(H[r * 256 + k], fW3[k * 29 + c], acc);
        float v = (acc - bn_mean[c]) * rsqrtf(bn_var[c] + 1e-5f) * bn_gamma[c] + bn_beta[c];
        Y[r * 29 + c] = fmaxf(v, 0.f);
    }
    __syncthreads();
    if (tid < 8) {
        int r = tid;
        float s = fb4[0];
#pragma unroll
        for (int c = 0; c < 29; c++) s = fmaf(Y[r * 29 + c], fW4[c], s);
        float score = 1.f / (1.f + expf(-s));
        int g = RB + r;
        int b = g >> 9;
        int rem = g & 511;
        int si = rem >> 5, n = rem & 31;
        float label = (x_label[b * S_ + si] == att_label[b * N_ + n]) ? 1.f : 0.f;
        float d = label - score;
        partial[r] = d * d;
    }
    __syncthreads();
    if (tid == 0) {
        float s = 0.f;
#pragma unroll
        for (int r = 0; r < 8; r++) s += partial[r];
        atomicAdd(out, s);
    }
}

extern "C" void kernel_launch(void* const* d_in, const int* in_sizes, int n_in,
                              void* d_out, int out_size, void* d_ws, size_t ws_size,
                              hipStream_t stream) {
    const float* x_f      = (const float*)d_in[0];
    const float* att      = (const float*)d_in[1];
    const int*   x_label  = (const int*)d_in[2];
    const int*   att_label= (const int*)d_in[3];
    const float* attW1    = (const float*)d_in[4];
    const float* attb1    = (const float*)d_in[5];
    const float* attW2    = (const float*)d_in[6];
    const float* attb2    = (const float*)d_in[7];
    const float* gW1      = (const float*)d_in[8];
    const float* gb1      = (const float*)d_in[9];
    const float* gW2      = (const float*)d_in[10];
    const float* gb2      = (const float*)d_in[11];
    const float* gW3      = (const float*)d_in[12];
    const float* gb3      = (const float*)d_in[13];
    const float* gW4      = (const float*)d_in[14];
    const float* gb4      = (const float*)d_in[15];
    const float* fW1      = (const float*)d_in[16];
    const float* fb1      = (const float*)d_in[17];
    const float* fW2      = (const float*)d_in[18];
    const float* fb2      = (const float*)d_in[19];
    const float* fW3      = (const float*)d_in[20];
    const float* fb3      = (const float*)d_in[21];
    const float* bn_gamma = (const float*)d_in[22];
    const float* bn_beta  = (const float*)d_in[23];
    const float* bn_mean  = (const float*)d_in[24];
    const float* bn_var   = (const float*)d_in[25];
    const float* fW4      = (const float*)d_in[26];
    const float* fb4      = (const float*)d_in[27];

    float* ws    = (float*)d_ws;
    float* a_buf = ws;                         // 65536 f
    float* ha    = ws + 65536;                 // 32768 f
    float* hx    = ws + 98304;                 // 1638400 f
    float* hsum  = ws + 1736704;               // 524288 f
    unsigned short* Whi = (unsigned short*)(ws + 2260992);   // 196608 us (98304 f)
    unsigned short* Wlo = (unsigned short*)(ws + 2359296);   // 196608 us (98304 f)
    // total ws: 2457600 floats = 9.83 MB

    hipMemsetAsync(d_out, 0, sizeof(float), stream);
    hipMemsetAsync(hsum, 0, (size_t)2048 * 256 * sizeof(float), stream);

    k_att1<<<128, 256, 0, stream>>>(att, attW1, attb1, a_buf);
    k_att2<<<128, 256, 0, stream>>>(a_buf, attW2, attb2, gW1, ha);
    k_hx<<<256, 512, 0, stream>>>(x_f, gW1, hx);
    k_wprep<<<768, 256, 0, stream>>>(gW2, gW3, gW4, Whi, Wlo);
    k_main<<<3200, 256, 0, stream>>>(hx, ha, gb1, Whi, Wlo, gb2, gb3, gb4, hsum);
    k_head<<<256, 256, 0, stream>>>(hsum, fW1, fb1, fW2, fb2, fW3, fb3,
                                    bn_gamma, bn_beta, bn_mean, bn_var,
                                    fW4, fb4, x_label, att_label, (float*)d_out);
}

// Round 4
// 592.700 us; speedup vs baseline: 2.4833x; 1.2860x over previous
//
#include <hip/hip_runtime.h>
#include <math.h>

#define B_ 4
#define S_ 16
#define N_ 32
#define C_ 512
#define D_ 10
#define DD_ 100
#define ATT_IN_ 312
#define ATT_H_ 512
#define ATT_DIM_ 514
#define CX_ 514

typedef __attribute__((ext_vector_type(8))) _Float16 half8;
typedef __attribute__((ext_vector_type(4))) _Float16 half4v;
typedef __attribute__((ext_vector_type(4))) float floatx4;

// ---------------- K1: a = relu(att @ attW1 + attb1)   (128 x 512, K=312)
__global__ void k_att1(const float* __restrict__ att, const float* __restrict__ W1,
                       const float* __restrict__ b1, float* __restrict__ a_out) {
    __shared__ float row[ATT_IN_];
    int r = blockIdx.x;
    int tid = threadIdx.x;
    for (int k = tid; k < ATT_IN_; k += 256) row[k] = att[r * ATT_IN_ + k];
    __syncthreads();
    float acc0 = b1[tid], acc1 = b1[tid + 256];
#pragma unroll 4
    for (int k = 0; k < ATT_IN_; k++) {
        float v = row[k];
        acc0 = fmaf(v, W1[k * 512 + tid], acc0);
        acc1 = fmaf(v, W1[k * 512 + tid + 256], acc1);
    }
    a_out[r * 512 + tid] = fmaxf(acc0, 0.f);
    a_out[r * 512 + tid + 256] = fmaxf(acc1, 0.f);
}

// ---------------- K2+K3 fused: att_f = relu(a @ attW2 + attb2); ha = att_f @ gW1[514:]
__global__ void k_att2(const float* __restrict__ a_in, const float* __restrict__ W2,
                       const float* __restrict__ b2, const float* __restrict__ gW1,
                       float* __restrict__ ha) {
    __shared__ float arow[512];
    __shared__ float frow[ATT_DIM_];
    int r = blockIdx.x;
    int tid = threadIdx.x;
    for (int k = tid; k < 512; k += 256) arow[k] = a_in[r * 512 + k];
    __syncthreads();
    for (int o = tid; o < ATT_DIM_; o += 256) {
        float acc = b2[o];
#pragma unroll 4
        for (int k = 0; k < 512; k++) acc = fmaf(arow[k], W2[k * ATT_DIM_ + o], acc);
        frow[o] = fmaxf(acc, 0.f);
    }
    __syncthreads();
    {
        int o = tid;
        float acc = 0.f;
#pragma unroll 4
        for (int k = 0; k < ATT_DIM_; k++) acc = fmaf(frow[k], gW1[(CX_ + k) * 256 + o], acc);
        ha[r * 256 + o] = acc;
    }
}

// ---------------- K4: hx[bs][p][c] = sum_k xc[bs,p,k] * gW1[k][c]
__global__ __launch_bounds__(512) void k_hx(const float* __restrict__ x_f,
                                            const float* __restrict__ gW1,
                                            float* __restrict__ hx) {
    __shared__ float At[32 * 128];
    int bs = blockIdx.x >> 2, cb = blockIdx.x & 3;
    int tid = threadIdx.x;
    int colg = tid & 15, rowg = tid >> 4;
    int cbase = cb * 64 + colg * 4;
    float acc[4][4] = {};
    const float* xb = x_f + (size_t)bs * C_ * DD_;
    int cl = tid >> 4;
    int p0 = (tid & 15) * 8;
    for (int kt = 0; kt < 16; kt++) {
        __syncthreads();
        {
            int c = kt * 32 + cl;
            float4 v0 = make_float4(0, 0, 0, 0), v1 = make_float4(0, 0, 0, 0);
            if (p0 + 4 <= DD_) v0 = *(const float4*)&xb[c * DD_ + p0];
            if (p0 + 8 <= DD_) v1 = *(const float4*)&xb[c * DD_ + p0 + 4];
            *(float4*)&At[cl * 128 + p0] = v0;
            *(float4*)&At[cl * 128 + p0 + 4] = v1;
        }
        __syncthreads();
#pragma unroll 4
        for (int k2 = 0; k2 < 32; k2++) {
            float4 w = *(const float4*)&gW1[(kt * 32 + k2) * 256 + cbase];
            float4 a = *(const float4*)&At[k2 * 128 + rowg * 4];
            float av[4] = {a.x, a.y, a.z, a.w};
            float wv[4] = {w.x, w.y, w.z, w.w};
#pragma unroll
            for (int i = 0; i < 4; i++)
#pragma unroll
                for (int j = 0; j < 4; j++) acc[i][j] = fmaf(av[i], wv[j], acc[i][j]);
        }
    }
    float4 w512 = *(const float4*)&gW1[512 * 256 + cbase];
    float4 w513 = *(const float4*)&gW1[513 * 256 + cbase];
    float wa[4] = {w512.x, w512.y, w512.z, w512.w};
    float wb[4] = {w513.x, w513.y, w513.z, w513.w};
#pragma unroll
    for (int i = 0; i < 4; i++) {
        int p = rowg * 4 + i;
        if (p < DD_) {
            float ci = (float)(p / 10) * 0.1f;
            float cj = (float)(p % 10) * 0.1f;
            float ov[4];
#pragma unroll
            for (int j = 0; j < 4; j++) ov[j] = acc[i][j] + ci * wa[j] + cj * wb[j];
            *(float4*)&hx[((size_t)bs * DD_ + p) * 256 + cbase] =
                make_float4(ov[0], ov[1], ov[2], ov[3]);
        }
    }
}

// ---------------- W prep: gW2/3/4 -> fp16 in MFMA-fragment-linear layout.
// Frag element (L, ks, ct, lane, j): k = ks*32 + (lane>>4)*8 + j, col = ct*16 + (lane&15).
__global__ void k_wprep(const float* __restrict__ gW2, const float* __restrict__ gW3,
                        const float* __restrict__ gW4, _Float16* __restrict__ Wf) {
    int f = blockIdx.x * 256 + threadIdx.x;        // 3 * 65536
    int j = f & 7, lane = (f >> 3) & 63, ct = (f >> 9) & 15, ks = (f >> 13) & 7, L = f >> 16;
    const float* W = (L == 0) ? gW2 : (L == 1) ? gW3 : gW4;
    int k = ks * 32 + ((lane >> 4) << 3) + j;
    int col = ct * 16 + (lane & 15);
    Wf[f] = (_Float16)W[k * 256 + col];
}

// ---------------- Main (fp16 MFMA, single pass): h0=relu(hx+ha+gb1) -> 3 layers -> p-sum
// Block: 64 rows x 256 cols, 256 thr = 4 waves, PURE COLUMN SPLIT (wave w owns cols
// w*64..w*64+63, all 64 rows) -> every W fragment read exactly once per block (dup-1).
// A in LDS: frag-linear fp16, region (ks 0..7, rt 0..3) of 64 lanes x 8 halves = 1 KB;
// A-frag = one ds_read_b128. 32 KB + 2 KB Pf -> 4 blocks/CU by LDS.
__global__ __launch_bounds__(256, 3) void k_main(
    const float* __restrict__ hx, const float* __restrict__ ha,
    const float* __restrict__ gb1, const _Float16* __restrict__ Wf,
    const float* __restrict__ gb2, const float* __restrict__ gb3,
    const float* __restrict__ gb4, float* __restrict__ hsum) {
    __shared__ _Float16 As16[16384];               // 32 KB, frag-linear
    __shared__ float Pf[512];                      // p-sum partials (2 segments x 256)
    int bs = blockIdx.x / 50, blk = blockIdx.x % 50;
    int R0 = blk * 64;
    int b = bs >> 4;
    int tid = threadIdx.x;
    int l = tid & 63;
    int wc = tid >> 6;                             // wave -> column quarter

    Pf[tid] = 0.f;
    Pf[tid + 256] = 0.f;

    // ---- stage h0 = relu(hx + ha + gb1) -> fp16 frag-layout LDS ----
    {
        int i = tid >> 2, q4 = tid & 3;            // row i (0..63), k-quarter q4
        int rl = R0 + i;
        int n = rl / 100, p = rl - n * 100;
        const float4* xr = (const float4*)(hx + ((size_t)bs * DD_ + p) * 256 + q4 * 64);
        const float4* ar = (const float4*)(ha + (size_t)(b * N_ + n) * 256 + q4 * 64);
        const float4* br = (const float4*)(gb1 + q4 * 64);
        int rt = i >> 4;
        int la_lo = i & 15;
#pragma unroll
        for (int c4 = 0; c4 < 16; c4++) {
            float4 x = xr[c4], a = ar[c4], bb = br[c4];
            half4v hv;
            hv[0] = (_Float16)fmaxf(x.x + a.x + bb.x, 0.f);
            hv[1] = (_Float16)fmaxf(x.y + a.y + bb.y, 0.f);
            hv[2] = (_Float16)fmaxf(x.z + a.z + bb.z, 0.f);
            hv[3] = (_Float16)fmaxf(x.w + a.w + bb.w, 0.f);
            int k0 = q4 * 64 + c4 * 4;
            int ks = k0 >> 5;
            int lane_addr = la_lo | (((k0 >> 3) & 3) << 4);
            *(half4v*)&As16[((ks * 4 + rt) << 9) + lane_addr * 8 + (k0 & 7)] = hv;
        }
    }
    __syncthreads();

    const float* biases[3] = {gb2, gb3, gb4};
    floatx4 acc[4][4];
    for (int layer = 0; layer < 3; layer++) {
#pragma unroll
        for (int ti = 0; ti < 4; ti++)
#pragma unroll
            for (int tj = 0; tj < 4; tj++) acc[ti][tj] = (floatx4){0.f, 0.f, 0.f, 0.f};

        const _Float16* WfL = Wf + layer * 65536;
#pragma unroll 2
        for (int ks = 0; ks < 8; ks++) {
            half8 afrag[4];
#pragma unroll
            for (int ti = 0; ti < 4; ti++)
                afrag[ti] = *(const half8*)&As16[((ks * 4 + ti) << 9) + l * 8];
#pragma unroll
            for (int tj = 0; tj < 4; tj++) {
                int ct = wc * 4 + tj;
                half8 bfrag = *(const half8*)(WfL + (size_t)((ks * 16 + ct) * 64 + l) * 8);
#pragma unroll
                for (int ti = 0; ti < 4; ti++)
                    acc[ti][tj] = __builtin_amdgcn_mfma_f32_16x16x32_f16(afrag[ti], bfrag, acc[ti][tj], 0, 0, 0);
            }
        }
        __syncthreads();                            // all reads of As16 done

        if (layer < 2) {
            const float* bias = biases[layer];
#pragma unroll
            for (int tj = 0; tj < 4; tj++) {
                int col = wc * 64 + tj * 16 + (l & 15);
                float bv = bias[col];
                int base = ((col >> 5) * 4) << 9;   // + ti*512 below
                int lane_hi = ((col >> 3) & 3) << 4;
                int jj = col & 7;
#pragma unroll
                for (int ti = 0; ti < 4; ti++) {
#pragma unroll
                    for (int r = 0; r < 4; r++) {
                        float v = fmaxf(acc[ti][tj][r] + bv, 0.f);
                        int row_lo = (l >> 4) * 4 + r;           // row&15
                        As16[base + (ti << 9) + (row_lo | lane_hi) * 8 + jj] = (_Float16)v;
                    }
                }
            }
            __syncthreads();
        } else {
            // relu + p-sum over the 64 rows (<=2 n-segments), LDS atomics then global
            int n0 = R0 / 100;
            int bound = (n0 + 1) * 100;
            const float* bias = biases[2];
#pragma unroll
            for (int tj = 0; tj < 4; tj++) {
                int col = wc * 64 + tj * 16 + (l & 15);
                float bv = bias[col];
                float p0 = 0.f, p1 = 0.f;
#pragma unroll
                for (int ti = 0; ti < 4; ti++) {
#pragma unroll
                    for (int r = 0; r < 4; r++) {
                        int rl = R0 + ti * 16 + (l >> 4) * 4 + r;
                        float v = fmaxf(acc[ti][tj][r] + bv, 0.f);
                        bool in1 = rl >= bound;
                        p0 += in1 ? 0.f : v;
                        p1 += in1 ? v : 0.f;
                    }
                }
                atomicAdd(&Pf[col], p0);
                atomicAdd(&Pf[256 + col], p1);
            }
            __syncthreads();
            {
                int n_last = (R0 + 63) / 100;
                atomicAdd(&hsum[((size_t)bs * N_ + n0) * 256 + tid], Pf[tid]);
                if (n0 + 1 <= n_last)
                    atomicAdd(&hsum[((size_t)bs * N_ + n0 + 1) * 256 + tid], Pf[tid + 256]);
            }
        }
    }
}

// ---------------- Head: hsum -> f1 -> f2 -> y(29) -> BN -> relu -> score -> loss
__global__ void k_head(const float* __restrict__ hsum,
                       const float* __restrict__ fW1, const float* __restrict__ fb1,
                       const float* __restrict__ fW2, const float* __restrict__ fb2,
                       const float* __restrict__ fW3, const float* __restrict__ fb3,
                       const float* __restrict__ bn_gamma, const float* __restrict__ bn_beta,
                       const float* __restrict__ bn_mean, const float* __restrict__ bn_var,
                       const float* __restrict__ fW4, const float* __restrict__ fb4,
                       const int* __restrict__ x_label, const int* __restrict__ att_label,
                       float* __restrict__ out) {
    __shared__ float H[8 * 256];
    __shared__ float Y[8 * 29];
    __shared__ float partial[8];
    int RB = blockIdx.x * 8;
    int tid = threadIdx.x;
    {
        int r = tid >> 5, c0 = (tid & 31) * 8;
#pragma unroll
        for (int cc = 0; cc < 8; cc++)
            H[r * 256 + c0 + cc] = hsum[(size_t)(RB + r) * 256 + c0 + cc];
    }
    __syncthreads();
    const float* Ws[2] = {fW1, fW2};
    const float* Bs[2] = {fb1, fb2};
#pragma unroll
    for (int layer = 0; layer < 2; layer++) {
        float acc[8];
#pragma unroll
        for (int r = 0; r < 8; r++) acc[r] = Bs[layer][tid];
        const float* W = Ws[layer];
#pragma unroll 4
        for (int k = 0; k < 256; k++) {
            float w = W[k * 256 + tid];
#pragma unroll
            for (int r = 0; r < 8; r++) acc[r] = fmaf(H[r * 256 + k], w, acc[r]);
        }
        __syncthreads();
#pragma unroll
        for (int r = 0; r < 8; r++) H[r * 256 + tid] = fmaxf(acc[r], 0.f);
        __syncthreads();
    }
    if (tid < 8 * 29) {
        int r = tid / 29, c = tid % 29;
        float acc = fb3[c];
#pragma unroll 4
        for (int k = 0; k < 256; k++) acc = fmaf(H[r * 256 + k], fW3[k * 29 + c], acc);
        float v = (acc - bn_mean[c]) * rsqrtf(bn_var[c] + 1e-5f) * bn_gamma[c] + bn_beta[c];
        Y[r * 29 + c] = fmaxf(v, 0.f);
    }
    __syncthreads();
    if (tid < 8) {
        int r = tid;
        float s = fb4[0];
#pragma unroll
        for (int c = 0; c < 29; c++) s = fmaf(Y[r * 29 + c], fW4[c], s);
        float score = 1.f / (1.f + expf(-s));
        int g = RB + r;
        int b = g >> 9;
        int rem = g & 511;
        int si = rem >> 5, n = rem & 31;
        float label = (x_label[b * S_ + si] == att_label[b * N_ + n]) ? 1.f : 0.f;
        float d = label - score;
        partial[r] = d * d;
    }
    __syncthreads();
    if (tid == 0) {
        float s = 0.f;
#pragma unroll
        for (int r = 0; r < 8; r++) s += partial[r];
        atomicAdd(out, s);
    }
}

extern "C" void kernel_launch(void* const* d_in, const int* in_sizes, int n_in,
                              void* d_out, int out_size, void* d_ws, size_t ws_size,
                              hipStream_t stream) {
    const float* x_f      = (const float*)d_in[0];
    const float* att      = (const float*)d_in[1];
    const int*   x_label  = (const int*)d_in[2];
    const int*   att_label= (const int*)d_in[3];
    const float* attW1    = (const float*)d_in[4];
    const float* attb1    = (const float*)d_in[5];
    const float* attW2    = (const float*)d_in[6];
    const float* attb2    = (const float*)d_in[7];
    const float* gW1      = (const float*)d_in[8];
    const float* gb1      = (const float*)d_in[9];
    const float* gW2      = (const float*)d_in[10];
    const float* gb2      = (const float*)d_in[11];
    const float* gW3      = (const float*)d_in[12];
    const float* gb3      = (const float*)d_in[13];
    const float* gW4      = (const float*)d_in[14];
    const float* gb4      = (const float*)d_in[15];
    const float* fW1      = (const float*)d_in[16];
    const float* fb1      = (const float*)d_in[17];
    const float* fW2      = (const float*)d_in[18];
    const float* fb2      = (const float*)d_in[19];
    const float* fW3      = (const float*)d_in[20];
    const float* fb3      = (const float*)d_in[21];
    const float* bn_gamma = (const float*)d_in[22];
    const float* bn_beta  = (const float*)d_in[23];
    const float* bn_mean  = (const float*)d_in[24];
    const float* bn_var   = (const float*)d_in[25];
    const float* fW4      = (const float*)d_in[26];
    const float* fb4      = (const float*)d_in[27];

    float* ws    = (float*)d_ws;
    float* a_buf = ws;                         // 65536 f
    float* ha    = ws + 65536;                 // 32768 f
    float* hx    = ws + 98304;                 // 1638400 f
    float* hsum  = ws + 1736704;               // 524288 f
    _Float16* Wf = (_Float16*)(ws + 2260992);  // 196608 halves (98304 f)
    // total ws: 2359296 floats = 9.44 MB

    hipMemsetAsync(d_out, 0, sizeof(float), stream);
    hipMemsetAsync(hsum, 0, (size_t)2048 * 256 * sizeof(float), stream);

    k_att1<<<128, 256, 0, stream>>>(att, attW1, attb1, a_buf);
    k_att2<<<128, 256, 0, stream>>>(a_buf, attW2, attb2, gW1, ha);
    k_hx<<<256, 512, 0, stream>>>(x_f, gW1, hx);
    k_wprep<<<768, 256, 0, stream>>>(gW2, gW3, gW4, Wf);
    k_main<<<3200, 256, 0, stream>>>(hx, ha, gb1, Wf, gb2, gb3, gb4, hsum);
    k_head<<<256, 256, 0, stream>>>(hsum, fW1, fb1, fW2, fb2, fW3, fb3,
                                    bn_gamma, bn_beta, bn_mean, bn_var,
                                    fW4, fb4, x_label, att_label, (float*)d_out);
}

// Round 6
// 454.659 us; speedup vs baseline: 3.2372x; 1.3036x over previous
//
#include <hip/hip_runtime.h>
#include <math.h>

#define B_ 4
#define S_ 16
#define N_ 32
#define C_ 512
#define D_ 10
#define DD_ 100
#define ATT_IN_ 312
#define ATT_H_ 512
#define ATT_DIM_ 514
#define CX_ 514

typedef __attribute__((ext_vector_type(8))) _Float16 half8;
typedef __attribute__((ext_vector_type(4))) _Float16 half4v;
typedef __attribute__((ext_vector_type(4))) float floatx4;

// ---------------- Fused att chain: att(128x312) -> a(512) -> att_f(514) -> ha(256)
// One block per row (128 blocks x 512 thr). All weight reads lane-coalesced.
// Deep ILP via 2x8 double-buffered register pipeline (16 loads in flight, static idx).
__global__ __launch_bounds__(512) void k_att(
    const float* __restrict__ att, const float* __restrict__ attW1,
    const float* __restrict__ attb1, const float* __restrict__ attW2,
    const float* __restrict__ attb2, const float* __restrict__ gW1,
    float* __restrict__ ha) {
    __shared__ float in_row[ATT_IN_];
    __shared__ float arow[512];
    __shared__ float frow[ATT_DIM_];
    __shared__ float Pc[512];
    int r = blockIdx.x;            // 0..127
    int tid = threadIdx.x;         // 0..511

    if (tid < ATT_IN_) in_row[tid] = att[r * ATT_IN_ + tid];
    __syncthreads();

#define LD8(buf, Wp, stride, g) { _Pragma("unroll") \
    for (int u = 0; u < 8; u++) buf[u] = Wp[((g) * 8 + u) * (stride)]; }
#define FM8(buf, src, acc, g) { _Pragma("unroll") \
    for (int u = 0; u < 8; u++) acc = fmaf(src[(g) * 8 + u], buf[u], acc); }

    // ---- phase A: arow[tid] = relu(sum_k in_row[k] * attW1[k][tid] + b1) ; K=312=39x8
    {
        const float* Wp = attW1 + tid;
        float acc = attb1[tid];
        float wA[8], wB[8];
        LD8(wA, Wp, 512, 0);
#pragma unroll
        for (int g = 0; g < 36; g += 2) {
            LD8(wB, Wp, 512, g + 1); FM8(wA, in_row, acc, g);
            LD8(wA, Wp, 512, g + 2); FM8(wB, in_row, acc, g + 1);
        }
        LD8(wB, Wp, 512, 37); FM8(wA, in_row, acc, 36); FM8(wB, in_row, acc, 37);
        LD8(wA, Wp, 512, 38); FM8(wA, in_row, acc, 38);
        arow[tid] = fmaxf(acc, 0.f);
    }
    __syncthreads();

    // ---- phase B: frow[o] = relu(sum_k arow[k] * attW2[k][o] + b2) ; K=512=64x8
    {
        const float* Wp = attW2 + tid;
        float acc = attb2[tid];
        float wA[8], wB[8];
        LD8(wA, Wp, 514, 0);
#pragma unroll
        for (int g = 0; g < 62; g += 2) {
            LD8(wB, Wp, 514, g + 1); FM8(wA, arow, acc, g);
            LD8(wA, Wp, 514, g + 2); FM8(wB, arow, acc, g + 1);
        }
        LD8(wB, Wp, 514, 63); FM8(wA, arow, acc, 62); FM8(wB, arow, acc, 63);
        frow[tid] = fmaxf(acc, 0.f);
    }
    // ragged cols 512,513: one wave each, split-K 64-way + butterfly reduce
    if (tid < 128) {
        int w = tid >> 6, lane = tid & 63;
        const float* Wc = attW2 + 512 + w;
        float p = 0.f;
#pragma unroll
        for (int m = 0; m < 8; m++) {
            int k = lane + m * 64;
            p = fmaf(arow[k], Wc[k * 514], p);
        }
#pragma unroll
        for (int off = 32; off; off >>= 1) p += __shfl_xor(p, off);
        if (lane == 0) frow[512 + w] = fmaxf(p + attb2[512 + w], 0.f);
    }
    __syncthreads();

    // ---- phase C: ha[o] = sum_k frow[k] * gW1[CX_+k][o] ; K=514, split-K by 2
    {
        int o = tid & 255, h = tid >> 8;           // h=0: k 0..255, h=1: k 256..513
        const float* Wp = gW1 + (size_t)(CX_ + h * 256) * 256 + o;
        const float* fr = frow + h * 256;
        float acc = 0.f;
        float wA[8], wB[8];
        LD8(wA, Wp, 256, 0);
#pragma unroll
        for (int g = 0; g < 30; g += 2) {
            LD8(wB, Wp, 256, g + 1); FM8(wA, fr, acc, g);
            LD8(wA, Wp, 256, g + 2); FM8(wB, fr, acc, g + 1);
        }
        LD8(wB, Wp, 256, 31); FM8(wA, fr, acc, 30); FM8(wB, fr, acc, 31);
        if (h == 1) {                               // tail k = 512, 513
            acc = fmaf(fr[256], Wp[256 * 256], acc);
            acc = fmaf(fr[257], Wp[257 * 256], acc);
        }
        Pc[tid] = acc;
    }
    __syncthreads();
    if (tid < 256) ha[r * 256 + tid] = Pc[tid] + Pc[tid + 256];
#undef LD8
#undef FM8
}

// ---------------- K4: hx[bs][p][c] = sum_k xc[bs,p,k] * gW1[k][c]
__global__ __launch_bounds__(512) void k_hx(const float* __restrict__ x_f,
                                            const float* __restrict__ gW1,
                                            float* __restrict__ hx) {
    __shared__ float At[32 * 128];
    int bs = blockIdx.x >> 2, cb = blockIdx.x & 3;
    int tid = threadIdx.x;
    int colg = tid & 15, rowg = tid >> 4;
    int cbase = cb * 64 + colg * 4;
    float acc[4][4] = {};
    const float* xb = x_f + (size_t)bs * C_ * DD_;
    int cl = tid >> 4;
    int p0 = (tid & 15) * 8;
    for (int kt = 0; kt < 16; kt++) {
        __syncthreads();
        {
            int c = kt * 32 + cl;
            float4 v0 = make_float4(0, 0, 0, 0), v1 = make_float4(0, 0, 0, 0);
            if (p0 + 4 <= DD_) v0 = *(const float4*)&xb[c * DD_ + p0];
            if (p0 + 8 <= DD_) v1 = *(const float4*)&xb[c * DD_ + p0 + 4];
            *(float4*)&At[cl * 128 + p0] = v0;
            *(float4*)&At[cl * 128 + p0 + 4] = v1;
        }
        __syncthreads();
#pragma unroll 8
        for (int k2 = 0; k2 < 32; k2++) {
            float4 w = *(const float4*)&gW1[(kt * 32 + k2) * 256 + cbase];
            float4 a = *(const float4*)&At[k2 * 128 + rowg * 4];
            float av[4] = {a.x, a.y, a.z, a.w};
            float wv[4] = {w.x, w.y, w.z, w.w};
#pragma unroll
            for (int i = 0; i < 4; i++)
#pragma unroll
                for (int j = 0; j < 4; j++) acc[i][j] = fmaf(av[i], wv[j], acc[i][j]);
        }
    }
    float4 w512 = *(const float4*)&gW1[512 * 256 + cbase];
    float4 w513 = *(const float4*)&gW1[513 * 256 + cbase];
    float wa[4] = {w512.x, w512.y, w512.z, w512.w};
    float wb[4] = {w513.x, w513.y, w513.z, w513.w};
#pragma unroll
    for (int i = 0; i < 4; i++) {
        int p = rowg * 4 + i;
        if (p < DD_) {
            float ci = (float)(p / 10) * 0.1f;
            float cj = (float)(p % 10) * 0.1f;
            float ov[4];
#pragma unroll
            for (int j = 0; j < 4; j++) ov[j] = acc[i][j] + ci * wa[j] + cj * wb[j];
            *(float4*)&hx[((size_t)bs * DD_ + p) * 256 + cbase] =
                make_float4(ov[0], ov[1], ov[2], ov[3]);
        }
    }
}

// ---------------- W prep: gW2/3/4 -> fp16 in MFMA-fragment-linear layout.
__global__ void k_wprep(const float* __restrict__ gW2, const float* __restrict__ gW3,
                        const float* __restrict__ gW4, _Float16* __restrict__ Wf) {
    int f = blockIdx.x * 256 + threadIdx.x;        // 3 * 65536
    int j = f & 7, lane = (f >> 3) & 63, ct = (f >> 9) & 15, ks = (f >> 13) & 7, L = f >> 16;
    const float* W = (L == 0) ? gW2 : (L == 1) ? gW3 : gW4;
    int k = ks * 32 + ((lane >> 4) << 3) + j;
    int col = ct * 16 + (lane & 15);
    Wf[f] = (_Float16)W[k * 256 + col];
}

// ---------------- Main (fp16 MFMA, single pass): h0=relu(hx+ha+gb1) -> 3 layers -> p-sum
__global__ __launch_bounds__(256, 3) void k_main(
    const float* __restrict__ hx, const float* __restrict__ ha,
    const float* __restrict__ gb1, const _Float16* __restrict__ Wf,
    const float* __restrict__ gb2, const float* __restrict__ gb3,
    const float* __restrict__ gb4, float* __restrict__ hsum) {
    __shared__ _Float16 As16[16384];               // 32 KB, frag-linear
    __shared__ float Pf[512];                      // p-sum partials (2 segments x 256)
    int bs = blockIdx.x / 50, blk = blockIdx.x % 50;
    int R0 = blk * 64;
    int b = bs >> 4;
    int tid = threadIdx.x;
    int l = tid & 63;
    int wc = tid >> 6;                             // wave -> column quarter

    Pf[tid] = 0.f;
    Pf[tid + 256] = 0.f;

    // ---- stage h0 = relu(hx + ha + gb1) -> fp16 frag-layout LDS ----
    {
        int i = tid >> 2, q4 = tid & 3;            // row i (0..63), k-quarter q4
        int rl = R0 + i;
        int n = rl / 100, p = rl - n * 100;
        const float4* xr = (const float4*)(hx + ((size_t)bs * DD_ + p) * 256 + q4 * 64);
        const float4* ar = (const float4*)(ha + (size_t)(b * N_ + n) * 256 + q4 * 64);
        const float4* br = (const float4*)(gb1 + q4 * 64);
        int rt = i >> 4;
        int la_lo = i & 15;
#pragma unroll
        for (int c4 = 0; c4 < 16; c4++) {
            float4 x = xr[c4], a = ar[c4], bb = br[c4];
            half4v hv;
            hv[0] = (_Float16)fmaxf(x.x + a.x + bb.x, 0.f);
            hv[1] = (_Float16)fmaxf(x.y + a.y + bb.y, 0.f);
            hv[2] = (_Float16)fmaxf(x.z + a.z + bb.z, 0.f);
            hv[3] = (_Float16)fmaxf(x.w + a.w + bb.w, 0.f);
            int k0 = q4 * 64 + c4 * 4;
            int ks = k0 >> 5;
            int lane_addr = la_lo | (((k0 >> 3) & 3) << 4);
            *(half4v*)&As16[((ks * 4 + rt) << 9) + lane_addr * 8 + (k0 & 7)] = hv;
        }
    }
    __syncthreads();

    const float* biases[3] = {gb2, gb3, gb4};
    floatx4 acc[4][4];
    for (int layer = 0; layer < 3; layer++) {
#pragma unroll
        for (int ti = 0; ti < 4; ti++)
#pragma unroll
            for (int tj = 0; tj < 4; tj++) acc[ti][tj] = (floatx4){0.f, 0.f, 0.f, 0.f};

        const _Float16* WfL = Wf + layer * 65536;
#pragma unroll 2
        for (int ks = 0; ks < 8; ks++) {
            half8 afrag[4];
#pragma unroll
            for (int ti = 0; ti < 4; ti++)
                afrag[ti] = *(const half8*)&As16[((ks * 4 + ti) << 9) + l * 8];
#pragma unroll
            for (int tj = 0; tj < 4; tj++) {
                int ct = wc * 4 + tj;
                half8 bfrag = *(const half8*)(WfL + (size_t)((ks * 16 + ct) * 64 + l) * 8);
#pragma unroll
                for (int ti = 0; ti < 4; ti++)
                    acc[ti][tj] = __builtin_amdgcn_mfma_f32_16x16x32_f16(afrag[ti], bfrag, acc[ti][tj], 0, 0, 0);
            }
        }
        __syncthreads();                            // all reads of As16 done

        if (layer < 2) {
            const float* bias = biases[layer];
#pragma unroll
            for (int tj = 0; tj < 4; tj++) {
                int col = wc * 64 + tj * 16 + (l & 15);
                float bv = bias[col];
                int base = ((col >> 5) * 4) << 9;   // + ti*512 below
                int lane_hi = ((col >> 3) & 3) << 4;
                int jj = col & 7;
#pragma unroll
                for (int ti = 0; ti < 4; ti++) {
#pragma unroll
                    for (int r = 0; r < 4; r++) {
                        float v = fmaxf(acc[ti][tj][r] + bv, 0.f);
                        int row_lo = (l >> 4) * 4 + r;           // row&15
                        As16[base + (ti << 9) + (row_lo | lane_hi) * 8 + jj] = (_Float16)v;
                    }
                }
            }
            __syncthreads();
        } else {
            // relu + p-sum over the 64 rows (<=2 n-segments), LDS atomics then global
            int n0 = R0 / 100;
            int bound = (n0 + 1) * 100;
            const float* bias = biases[2];
#pragma unroll
            for (int tj = 0; tj < 4; tj++) {
                int col = wc * 64 + tj * 16 + (l & 15);
                float bv = bias[col];
                float p0 = 0.f, p1 = 0.f;
#pragma unroll
                for (int ti = 0; ti < 4; ti++) {
#pragma unroll
                    for (int r = 0; r < 4; r++) {
                        int rl = R0 + ti * 16 + (l >> 4) * 4 + r;
                        float v = fmaxf(acc[ti][tj][r] + bv, 0.f);
                        bool in1 = rl >= bound;
                        p0 += in1 ? 0.f : v;
                        p1 += in1 ? v : 0.f;
                    }
                }
                atomicAdd(&Pf[col], p0);
                atomicAdd(&Pf[256 + col], p1);
            }
            __syncthreads();
            {
                int n_last = (R0 + 63) / 100;
                atomicAdd(&hsum[((size_t)bs * N_ + n0) * 256 + tid], Pf[tid]);
                if (n0 + 1 <= n_last)
                    atomicAdd(&hsum[((size_t)bs * N_ + n0 + 1) * 256 + tid], Pf[tid + 256]);
            }
        }
    }
}

// ---------------- Head: hsum -> f1 -> f2 -> y(29) -> BN -> relu -> score -> loss
__global__ void k_head(const float* __restrict__ hsum,
                       const float* __restrict__ fW1, const float* __restrict__ fb1,
                       const float* __restrict__ fW2, const float* __restrict__ fb2,
                       const float* __restrict__ fW3, const float* __restrict__ fb3,
                       const float* __restrict__ bn_gamma, const float* __restrict__ bn_beta,
                       const float* __restrict__ bn_mean, const float* __restrict__ bn_var,
                       const float* __restrict__ fW4, const float* __restrict__ fb4,
                       const int* __restrict__ x_label, const int* __restrict__ att_label,
                       float* __restrict__ out) {
    __shared__ float H[8 * 256];
    __shared__ float Y[8 * 29];
    __shared__ float partial[8];
    int RB = blockIdx.x * 8;
    int tid = threadIdx.x;
    {
        int r = tid >> 5, c0 = (tid & 31) * 8;
#pragma unroll
        for (int cc = 0; cc < 8; cc++)
            H[r * 256 + c0 + cc] = hsum[(size_t)(RB + r) * 256 + c0 + cc];
    }
    __syncthreads();
    const float* Ws[2] = {fW1, fW2};
    const float* Bs[2] = {fb1, fb2};
#pragma unroll
    for (int layer = 0; layer < 2; layer++) {
        float acc[8];
#pragma unroll
        for (int r = 0; r < 8; r++) acc[r] = Bs[layer][tid];
        const float* W = Ws[layer];
#pragma unroll 16
        for (int k = 0; k < 256; k++) {
            float w = W[k * 256 + tid];
#pragma unroll
            for (int r = 0; r < 8; r++) acc[r] = fmaf(H[r * 256 + k], w, acc[r]);
        }
        __syncthreads();
#pragma unroll
        for (int r = 0; r < 8; r++) H[r * 256 + tid] = fmaxf(acc[r], 0.f);
        __syncthreads();
    }
    if (tid < 8 * 29) {
        int r = tid / 29, c = tid % 29;
        float acc = fb3[c];
#pragma unroll 8
        for (int k = 0; k < 256; k++) acc = fmaf(H[r * 256 + k], fW3[k * 29 + c], acc);
        float v = (acc - bn_mean[c]) * rsqrtf(bn_var[c] + 1e-5f) * bn_gamma[c] + bn_beta[c];
        Y[r * 29 + c] = fmaxf(v, 0.f);
    }
    __syncthreads();
    if (tid < 8) {
        int r = tid;
        float s = fb4[0];
#pragma unroll
        for (int c = 0; c < 29; c++) s = fmaf(Y[r * 29 + c], fW4[c], s);
        float score = 1.f / (1.f + expf(-s));
        int g = RB + r;
        int b = g >> 9;
        int rem = g & 511;
        int si = rem >> 5, n = rem & 31;
        float label = (x_label[b * S_ + si] == att_label[b * N_ + n]) ? 1.f : 0.f;
        float d = label - score;
        partial[r] = d * d;
    }
    __syncthreads();
    if (tid == 0) {
        float s = 0.f;
#pragma unroll
        for (int r = 0; r < 8; r++) s += partial[r];
        atomicAdd(out, s);
    }
}

extern "C" void kernel_launch(void* const* d_in, const int* in_sizes, int n_in,
                              void* d_out, int out_size, void* d_ws, size_t ws_size,
                              hipStream_t stream) {
    const float* x_f      = (const float*)d_in[0];
    const float* att      = (const float*)d_in[1];
    const int*   x_label  = (const int*)d_in[2];
    const int*   att_label= (const int*)d_in[3];
    const float* attW1    = (const float*)d_in[4];
    const float* attb1    = (const float*)d_in[5];
    const float* attW2    = (const float*)d_in[6];
    const float* attb2    = (const float*)d_in[7];
    const float* gW1      = (const float*)d_in[8];
    const float* gb1      = (const float*)d_in[9];
    const float* gW2      = (const float*)d_in[10];
    const float* gb2      = (const float*)d_in[11];
    const float* gW3      = (const float*)d_in[12];
    const float* gb3      = (const float*)d_in[13];
    const float* gW4      = (const float*)d_in[14];
    const float* gb4      = (const float*)d_in[15];
    const float* fW1      = (const float*)d_in[16];
    const float* fb1      = (const float*)d_in[17];
    const float* fW2      = (const float*)d_in[18];
    const float* fb2      = (const float*)d_in[19];
    const float* fW3      = (const float*)d_in[20];
    const float* fb3      = (const float*)d_in[21];
    const float* bn_gamma = (const float*)d_in[22];
    const float* bn_beta  = (const float*)d_in[23];
    const float* bn_mean  = (const float*)d_in[24];
    const float* bn_var   = (const float*)d_in[25];
    const float* fW4      = (const float*)d_in[26];
    const float* fb4      = (const float*)d_in[27];

    float* ws    = (float*)d_ws;
    float* ha    = ws + 65536;                 // 32768 f
    float* hx    = ws + 98304;                 // 1638400 f
    float* hsum  = ws + 1736704;               // 524288 f
    _Float16* Wf = (_Float16*)(ws + 2260992);  // 196608 halves

    hipMemsetAsync(d_out, 0, sizeof(float), stream);
    hipMemsetAsync(hsum, 0, (size_t)2048 * 256 * sizeof(float), stream);

    k_att<<<128, 512, 0, stream>>>(att, attW1, attb1, attW2, attb2, gW1, ha);
    k_hx<<<256, 512, 0, stream>>>(x_f, gW1, hx);
    k_wprep<<<768, 256, 0, stream>>>(gW2, gW3, gW4, Wf);
    k_main<<<3200, 256, 0, stream>>>(hx, ha, gb1, Wf, gb2, gb3, gb4, hsum);
    k_head<<<256, 256, 0, stream>>>(hsum, fW1, fb1, fW2, fb2, fW3, fb3,
                                    bn_gamma, bn_beta, bn_mean, bn_var,
                                    fW4, fb4, x_label, att_label, (float*)d_out);
}

// Round 8
// 370.677 us; speedup vs baseline: 3.9707x; 1.2266x over previous
//
#include <hip/hip_runtime.h>
#include <math.h>

#define B_ 4
#define S_ 16
#define N_ 32
#define C_ 512
#define D_ 10
#define DD_ 100
#define ATT_IN_ 312
#define ATT_H_ 512
#define ATT_DIM_ 514
#define CX_ 514

typedef __attribute__((ext_vector_type(8))) _Float16 half8;
typedef __attribute__((ext_vector_type(4))) _Float16 half4v;
typedef __attribute__((ext_vector_type(4))) float floatx4;

// LDS frag-block swizzle: block' = la ^ (la>>3) ^ ks. Bijective per region
// (only bits 0-2 touched); b128 frag reads stay conflict-free under any lane
// bijection; scattered writes spread across all 8 bank-octets (<=2 lanes/bank).
__device__ __forceinline__ int SWZ(int la, int ks) { return la ^ (la >> 3) ^ (ks & 7); }

// ---------------- Fused att chain: att(128x312) -> a(512) -> att_f(514) -> ha(256)
__global__ __launch_bounds__(512) void k_att(
    const float* __restrict__ att, const float* __restrict__ attW1,
    const float* __restrict__ attb1, const float* __restrict__ attW2,
    const float* __restrict__ attb2, const float* __restrict__ gW1,
    float* __restrict__ ha) {
    __shared__ float in_row[ATT_IN_];
    __shared__ float arow[512];
    __shared__ float frow[ATT_DIM_];
    __shared__ float Pc[512];
    int r = blockIdx.x;            // 0..127
    int tid = threadIdx.x;         // 0..511

    if (tid < ATT_IN_) in_row[tid] = att[r * ATT_IN_ + tid];
    __syncthreads();

#define LD8(buf, Wp, stride, g) { _Pragma("unroll") \
    for (int u = 0; u < 8; u++) buf[u] = Wp[((g) * 8 + u) * (stride)]; }
#define FM8(buf, src, acc, g) { _Pragma("unroll") \
    for (int u = 0; u < 8; u++) acc = fmaf(src[(g) * 8 + u], buf[u], acc); }

    // ---- phase A: arow[tid] = relu(in_row @ attW1 + b1) ; K=312=39x8
    {
        const float* Wp = attW1 + tid;
        float acc = attb1[tid];
        float wA[8], wB[8];
        LD8(wA, Wp, 512, 0);
#pragma unroll
        for (int g = 0; g < 36; g += 2) {
            LD8(wB, Wp, 512, g + 1); FM8(wA, in_row, acc, g);
            LD8(wA, Wp, 512, g + 2); FM8(wB, in_row, acc, g + 1);
        }
        LD8(wB, Wp, 512, 37); FM8(wA, in_row, acc, 36); FM8(wB, in_row, acc, 37);
        LD8(wA, Wp, 512, 38); FM8(wA, in_row, acc, 38);
        arow[tid] = fmaxf(acc, 0.f);
    }
    __syncthreads();

    // ---- phase B: frow[o] = relu(arow @ attW2 + b2) ; K=512=64x8
    {
        const float* Wp = attW2 + tid;
        float acc = attb2[tid];
        float wA[8], wB[8];
        LD8(wA, Wp, 514, 0);
#pragma unroll
        for (int g = 0; g < 62; g += 2) {
            LD8(wB, Wp, 514, g + 1); FM8(wA, arow, acc, g);
            LD8(wA, Wp, 514, g + 2); FM8(wB, arow, acc, g + 1);
        }
        LD8(wB, Wp, 514, 63); FM8(wA, arow, acc, 62); FM8(wB, arow, acc, 63);
        frow[tid] = fmaxf(acc, 0.f);
    }
    // ragged cols 512,513
    if (tid < 128) {
        int w = tid >> 6, lane = tid & 63;
        const float* Wc = attW2 + 512 + w;
        float p = 0.f;
#pragma unroll
        for (int m = 0; m < 8; m++) {
            int k = lane + m * 64;
            p = fmaf(arow[k], Wc[k * 514], p);
        }
#pragma unroll
        for (int off = 32; off; off >>= 1) p += __shfl_xor(p, off);
        if (lane == 0) frow[512 + w] = fmaxf(p + attb2[512 + w], 0.f);
    }
    __syncthreads();

    // ---- phase C: ha[o] = frow @ gW1[CX_:] ; K=514, split-K by 2
    {
        int o = tid & 255, h = tid >> 8;
        const float* Wp = gW1 + (size_t)(CX_ + h * 256) * 256 + o;
        const float* fr = frow + h * 256;
        float acc = 0.f;
        float wA[8], wB[8];
        LD8(wA, Wp, 256, 0);
#pragma unroll
        for (int g = 0; g < 30; g += 2) {
            LD8(wB, Wp, 256, g + 1); FM8(wA, fr, acc, g);
            LD8(wA, Wp, 256, g + 2); FM8(wB, fr, acc, g + 1);
        }
        LD8(wB, Wp, 256, 31); FM8(wA, fr, acc, 30); FM8(wB, fr, acc, 31);
        if (h == 1) {
            acc = fmaf(fr[256], Wp[256 * 256], acc);
            acc = fmaf(fr[257], Wp[257 * 256], acc);
        }
        Pc[tid] = acc;
    }
    __syncthreads();
    if (tid < 256) ha[r * 256 + tid] = Pc[tid] + Pc[tid + 256];
#undef LD8
#undef FM8
}

// ---------------- W prep: gW2/3/4 (->Wf) and gW1[:512] (->Wxf) as fp16 frag-linear.
// Frag element (ks, ct, lane, j): k = ks*32 + (lane>>4)*8 + j, col = ct*16 + (lane&15).
__global__ void k_wprep(const float* __restrict__ gW1, const float* __restrict__ gW2,
                        const float* __restrict__ gW3, const float* __restrict__ gW4,
                        _Float16* __restrict__ Wf, _Float16* __restrict__ Wxf) {
    int f = blockIdx.x * 256 + threadIdx.x;        // 3*65536 (Wf) + 131072 (Wxf)
    if (f < 196608) {
        int j = f & 7, lane = (f >> 3) & 63, ct = (f >> 9) & 15, ks = (f >> 13) & 7, L = f >> 16;
        const float* W = (L == 0) ? gW2 : (L == 1) ? gW3 : gW4;
        int k = ks * 32 + ((lane >> 4) << 3) + j;
        int col = ct * 16 + (lane & 15);
        Wf[f] = (_Float16)W[k * 256 + col];
    } else {
        int g = f - 196608;
        int j = g & 7, lane = (g >> 3) & 63, ct = (g >> 9) & 15, ks = (g >> 13) & 15;
        int k = ks * 32 + ((lane >> 4) << 3) + j;
        int col = ct * 16 + (lane & 15);
        Wxf[g] = (_Float16)gW1[k * 256 + col];
    }
}

// ---------------- K4 (MFMA): hx[g][c] = sum_k xf16[g,k] * Wx[k,c] + coord epilogue
// 100 blocks x 256 thr (4 waves col-split 64). Rows g = bs*100+p flat (64/block).
// A-chunks (64 rows x 32 k fp16, 4KB) double-buffered; global loads issued pre-MFMA.
__global__ __launch_bounds__(256) void k_hx(const float* __restrict__ x_f,
                                            const float* __restrict__ gW1,
                                            const _Float16* __restrict__ Wxf,
                                            float* __restrict__ hx) {
    __shared__ _Float16 Ax[2][2048];
    int R0 = blockIdx.x * 64;
    int tid = threadIdx.x;
    int l = tid & 63, wc = tid >> 6;
    // staging geometry (fixed per thread): c_loc = k within chunk, 8 rows each
    int c_loc = tid >> 3;
    int r0s = (tid & 7) * 8;
    int sbase[8];                       // x_f flat base: (bs*512)*100 + p
    int srow_la[8], srow_rt[8];
#pragma unroll
    for (int u = 0; u < 8; u++) {
        int g = R0 + r0s + u;
        int bs = g / 100, p = g - bs * 100;
        sbase[u] = bs * 51200 + p;
        int row = r0s + u;
        srow_rt[u] = row >> 4;
        srow_la[u] = (row & 15) | (((c_loc >> 3) & 3) << 4);
    }
    int sj = c_loc & 7;

    // stage chunk 0
    {
        float xv[8];
#pragma unroll
        for (int u = 0; u < 8; u++) xv[u] = x_f[sbase[u] + c_loc * 100];
#pragma unroll
        for (int u = 0; u < 8; u++)
            Ax[0][srow_rt[u] * 512 + SWZ(srow_la[u], 0) * 8 + sj] = (_Float16)xv[u];
    }
    __syncthreads();

    floatx4 acc[4][4];
#pragma unroll
    for (int ti = 0; ti < 4; ti++)
#pragma unroll
        for (int tj = 0; tj < 4; tj++) acc[ti][tj] = (floatx4){0.f, 0.f, 0.f, 0.f};

    for (int ks = 0; ks < 16; ks++) {
        int cur = ks & 1;
        float xv[8];
        if (ks < 15) {
            int k1 = (ks + 1) * 32 + c_loc;
#pragma unroll
            for (int u = 0; u < 8; u++) xv[u] = x_f[sbase[u] + k1 * 100];
        }
#pragma unroll
        for (int ti = 0; ti < 4; ti++) {
            half8 afrag = *(const half8*)&Ax[cur][ti * 512 + SWZ(l, ks) * 8];
#pragma unroll
            for (int tj = 0; tj < 4; tj++) {
                int ct = wc * 4 + tj;
                half8 bfrag = *(const half8*)(Wxf + (size_t)((ks * 16 + ct) * 64 + l) * 8);
                acc[ti][tj] = __builtin_amdgcn_mfma_f32_16x16x32_f16(afrag, bfrag, acc[ti][tj], 0, 0, 0);
            }
        }
        if (ks < 15) {
#pragma unroll
            for (int u = 0; u < 8; u++)
                Ax[cur ^ 1][srow_rt[u] * 512 + SWZ(srow_la[u], ks + 1) * 8 + sj] = (_Float16)xv[u];
        }
        __syncthreads();
    }

    // epilogue: + coord channels, store fp32
#pragma unroll
    for (int tj = 0; tj < 4; tj++) {
        int col = wc * 64 + tj * 16 + (l & 15);
        float w512 = gW1[512 * 256 + col];
        float w513 = gW1[513 * 256 + col];
#pragma unroll
        for (int ti = 0; ti < 4; ti++) {
#pragma unroll
            for (int r = 0; r < 4; r++) {
                int g = R0 + ti * 16 + (l >> 4) * 4 + r;
                int bs = g / 100, p = g - bs * 100;
                float ci = (float)(p / 10) * 0.1f;
                float cj = (float)(p % 10) * 0.1f;
                hx[(size_t)(bs * 100 + p) * 256 + col] = acc[ti][tj][r] + ci * w512 + cj * w513;
            }
        }
    }
}

// ---------------- Main (fp16 MFMA): h0=relu(hx+ha+gb1) -> 3 layers -> p-sum
// 64 rows x 256 cols/block, 4 waves col-split; B-frags register-double-buffered
// across ks; LDS frag blocks SWZ-swizzled at all 3 touch points.
__global__ __launch_bounds__(256, 4) void k_main(
    const float* __restrict__ hx, const float* __restrict__ ha,
    const float* __restrict__ gb1, const _Float16* __restrict__ Wf,
    const float* __restrict__ gb2, const float* __restrict__ gb3,
    const float* __restrict__ gb4, float* __restrict__ hsum) {
    __shared__ _Float16 As16[16384];               // 32 KB, frag-linear (swizzled)
    __shared__ float Pf[512];
    int bs = blockIdx.x / 50, blk = blockIdx.x % 50;
    int R0 = blk * 64;
    int b = bs >> 4;
    int tid = threadIdx.x;
    int l = tid & 63;
    int wc = tid >> 6;

    Pf[tid] = 0.f;
    Pf[tid + 256] = 0.f;

    // ---- stage h0 = relu(hx + ha + gb1) -> fp16 frag-layout LDS ----
    {
        int i = tid >> 2, q4 = tid & 3;
        int rl = R0 + i;
        int n = rl / 100, p = rl - n * 100;
        const float4* xr = (const float4*)(hx + ((size_t)bs * DD_ + p) * 256 + q4 * 64);
        const float4* ar = (const float4*)(ha + (size_t)(b * N_ + n) * 256 + q4 * 64);
        const float4* br = (const float4*)(gb1 + q4 * 64);
        int rt = i >> 4;
        int la_lo = i & 15;
#pragma unroll
        for (int c4 = 0; c4 < 16; c4++) {
            float4 x = xr[c4], a = ar[c4], bb = br[c4];
            half4v hv;
            hv[0] = (_Float16)fmaxf(x.x + a.x + bb.x, 0.f);
            hv[1] = (_Float16)fmaxf(x.y + a.y + bb.y, 0.f);
            hv[2] = (_Float16)fmaxf(x.z + a.z + bb.z, 0.f);
            hv[3] = (_Float16)fmaxf(x.w + a.w + bb.w, 0.f);
            int k0 = q4 * 64 + c4 * 4;
            int ks = k0 >> 5;
            int la = la_lo | (((k0 >> 3) & 3) << 4);
            *(half4v*)&As16[((ks * 4 + rt) << 9) + SWZ(la, ks) * 8 + (k0 & 7)] = hv;
        }
    }
    __syncthreads();

    const float* biases[3] = {gb2, gb3, gb4};
    floatx4 acc[4][4];
    for (int layer = 0; layer < 3; layer++) {
#pragma unroll
        for (int ti = 0; ti < 4; ti++)
#pragma unroll
            for (int tj = 0; tj < 4; tj++) acc[ti][tj] = (floatx4){0.f, 0.f, 0.f, 0.f};

        const _Float16* WfL = Wf + layer * 65536;
        half8 bcur[4], bnxt[4];
#pragma unroll
        for (int tj = 0; tj < 4; tj++)
            bcur[tj] = *(const half8*)(WfL + (size_t)((0 * 16 + wc * 4 + tj) * 64 + l) * 8);
#pragma unroll
        for (int ks = 0; ks < 8; ks++) {
            if (ks < 7) {
#pragma unroll
                for (int tj = 0; tj < 4; tj++)
                    bnxt[tj] = *(const half8*)(WfL + (size_t)(((ks + 1) * 16 + wc * 4 + tj) * 64 + l) * 8);
            }
#pragma unroll
            for (int ti = 0; ti < 4; ti++) {
                half8 afrag = *(const half8*)&As16[((ks * 4 + ti) << 9) + SWZ(l, ks) * 8];
#pragma unroll
                for (int tj = 0; tj < 4; tj++)
                    acc[ti][tj] = __builtin_amdgcn_mfma_f32_16x16x32_f16(afrag, bcur[tj], acc[ti][tj], 0, 0, 0);
            }
#pragma unroll
            for (int tj = 0; tj < 4; tj++) bcur[tj] = bnxt[tj];
        }
        __syncthreads();

        if (layer < 2) {
            const float* bias = biases[layer];
#pragma unroll
            for (int tj = 0; tj < 4; tj++) {
                int col = wc * 64 + tj * 16 + (l & 15);
                float bv = bias[col];
                int ksp = col >> 5;
                int lane_hi = ((col >> 3) & 3) << 4;
                int jj = col & 7;
#pragma unroll
                for (int ti = 0; ti < 4; ti++) {
#pragma unroll
                    for (int r = 0; r < 4; r++) {
                        float v = fmaxf(acc[ti][tj][r] + bv, 0.f);
                        int la = ((l >> 4) * 4 + r) | lane_hi;
                        As16[((ksp * 4 + ti) << 9) + SWZ(la, ksp) * 8 + jj] = (_Float16)v;
                    }
                }
            }
            __syncthreads();
        } else {
            // relu + p-sum; shuffle pre-reduce (lanes l, l+16, l+32, l+48 share col)
            int n0 = R0 / 100;
            int bound = (n0 + 1) * 100;
            const float* bias = biases[2];
#pragma unroll
            for (int tj = 0; tj < 4; tj++) {
                int col = wc * 64 + tj * 16 + (l & 15);
                float bv = bias[col];
                float p0 = 0.f, p1 = 0.f;
#pragma unroll
                for (int ti = 0; ti < 4; ti++) {
#pragma unroll
                    for (int r = 0; r < 4; r++) {
                        int rl = R0 + ti * 16 + (l >> 4) * 4 + r;
                        float v = fmaxf(acc[ti][tj][r] + bv, 0.f);
                        bool in1 = rl >= bound;
                        p0 += in1 ? 0.f : v;
                        p1 += in1 ? v : 0.f;
                    }
                }
                p0 += __shfl_xor(p0, 16); p0 += __shfl_xor(p0, 32);
                p1 += __shfl_xor(p1, 16); p1 += __shfl_xor(p1, 32);
                if (l < 16) {
                    atomicAdd(&Pf[col], p0);
                    atomicAdd(&Pf[256 + col], p1);
                }
            }
            __syncthreads();
            {
                int n_last = (R0 + 63) / 100;
                atomicAdd(&hsum[((size_t)bs * N_ + n0) * 256 + tid], Pf[tid]);
                if (n0 + 1 <= n_last)
                    atomicAdd(&hsum[((size_t)bs * N_ + n0 + 1) * 256 + tid], Pf[tid + 256]);
            }
        }
    }
}

// ---------------- Head: hsum -> f1 -> f2 -> y(29) -> BN -> relu -> score -> loss
__global__ void k_head(const float* __restrict__ hsum,
                       const float* __restrict__ fW1, const float* __restrict__ fb1,
                       const float* __restrict__ fW2, const float* __restrict__ fb2,
                       const float* __restrict__ fW3, const float* __restrict__ fb3,
                       const float* __restrict__ bn_gamma, const float* __restrict__ bn_beta,
                       const float* __restrict__ bn_mean, const float* __restrict__ bn_var,
                       const float* __restrict__ fW4, const float* __restrict__ fb4,
                       const int* __restrict__ x_label, const int* __restrict__ att_label,
                       float* __restrict__ out) {
    __shared__ float H[8 * 256];
    __shared__ float Y[8 * 29];
    __shared__ float partial[8];
    int RB = blockIdx.x * 8;
    int tid = threadIdx.x;
    {
        int r = tid >> 5, c0 = (tid & 31) * 8;
#pragma unroll
        for (int cc = 0; cc < 8; cc++)
            H[r * 256 + c0 + cc] = hsum[(size_t)(RB + r) * 256 + c0 + cc];
    }
    __syncthreads();
    const float* Ws[2] = {fW1, fW2};
    const float* Bs[2] = {fb1, fb2};
#pragma unroll
    for (int layer = 0; layer < 2; layer++) {
        float acc[8];
#pragma unroll
        for (int r = 0; r < 8; r++) acc[r] = Bs[layer][tid];
        const float* W = Ws[layer];
#pragma unroll 16
        for (int k = 0; k < 256; k++) {
            float w = W[k * 256 + tid];
#pragma unroll
            for (int r = 0; r < 8; r++) acc[r] = fmaf(H[r * 256 + k], w, acc[r]);
        }
        __syncthreads();
#pragma unroll
        for (int r = 0; r < 8; r++) H[r * 256 + tid] = fmaxf(acc[r], 0.f);
        __syncthreads();
    }
    if (tid < 8 * 29) {
        int r = tid / 29, c = tid % 29;
        float acc = fb3[c];
#pragma unroll 8
        for (int k = 0; k < 256; k++) acc = fmaf(H[r * 256 + k], fW3[k * 29 + c], acc);
        float v = (acc - bn_mean[c]) * rsqrtf(bn_var[c] + 1e-5f) * bn_gamma[c] + bn_beta[c];
        Y[r * 29 + c] = fmaxf(v, 0.f);
    }
    __syncthreads();
    if (tid < 8) {
        int r = tid;
        float s = fb4[0];
#pragma unroll
        for (int c = 0; c < 29; c++) s = fmaf(Y[r * 29 + c], fW4[c], s);
        float score = 1.f / (1.f + expf(-s));
        int g = RB + r;
        int b = g >> 9;
        int rem = g & 511;
        int si = rem >> 5, n = rem & 31;
        float label = (x_label[b * S_ + si] == att_label[b * N_ + n]) ? 1.f : 0.f;
        float d = label - score;
        partial[r] = d * d;
    }
    __syncthreads();
    if (tid == 0) {
        float s = 0.f;
#pragma unroll
        for (int r = 0; r < 8; r++) s += partial[r];
        atomicAdd(out, s);
    }
}

extern "C" void kernel_launch(void* const* d_in, const int* in_sizes, int n_in,
                              void* d_out, int out_size, void* d_ws, size_t ws_size,
                              hipStream_t stream) {
    const float* x_f      = (const float*)d_in[0];
    const float* att      = (const float*)d_in[1];
    const int*   x_label  = (const int*)d_in[2];
    const int*   att_label= (const int*)d_in[3];
    const float* attW1    = (const float*)d_in[4];
    const float* attb1    = (const float*)d_in[5];
    const float* attW2    = (const float*)d_in[6];
    const float* attb2    = (const float*)d_in[7];
    const float* gW1      = (const float*)d_in[8];
    const float* gb1      = (const float*)d_in[9];
    const float* gW2      = (const float*)d_in[10];
    const float* gb2      = (const float*)d_in[11];
    const float* gW3      = (const float*)d_in[12];
    const float* gb3      = (const float*)d_in[13];
    const float* gW4      = (const float*)d_in[14];
    const float* gb4      = (const float*)d_in[15];
    const float* fW1      = (const float*)d_in[16];
    const float* fb1      = (const float*)d_in[17];
    const float* fW2      = (const float*)d_in[18];
    const float* fb2      = (const float*)d_in[19];
    const float* fW3      = (const float*)d_in[20];
    const float* fb3      = (const float*)d_in[21];
    const float* bn_gamma = (const float*)d_in[22];
    const float* bn_beta  = (const float*)d_in[23];
    const float* bn_mean  = (const float*)d_in[24];
    const float* bn_var   = (const float*)d_in[25];
    const float* fW4      = (const float*)d_in[26];
    const float* fb4      = (const float*)d_in[27];

    float* ws    = (float*)d_ws;
    float* ha    = ws + 65536;                    // 32768 f
    float* hx    = ws + 98304;                    // 1638400 f
    float* hsum  = ws + 1736704;                  // 524288 f
    _Float16* Wf  = (_Float16*)(ws + 2260992);    // 196608 halves (98304 f)
    _Float16* Wxf = (_Float16*)(ws + 2359296);    // 131072 halves (65536 f)
    // total ws: 2424832 floats = 9.70 MB

    hipMemsetAsync(d_out, 0, sizeof(float), stream);
    hipMemsetAsync(hsum, 0, (size_t)2048 * 256 * sizeof(float), stream);

    k_att<<<128, 512, 0, stream>>>(att, attW1, attb1, attW2, attb2, gW1, ha);
    k_wprep<<<1280, 256, 0, stream>>>(gW1, gW2, gW3, gW4, Wf, Wxf);
    k_hx<<<100, 256, 0, stream>>>(x_f, gW1, Wxf, hx);
    k_main<<<3200, 256, 0, stream>>>(hx, ha, gb1, Wf, gb2, gb3, gb4, hsum);
    k_head<<<256, 256, 0, stream>>>(hsum, fW1, fb1, fW2, fb2, fW3, fb3,
                                    bn_gamma, bn_beta, bn_mean, bn_var,
                                    fW4, fb4, x_label, att_label, (float*)d_out);
}

// Round 10
// 360.634 us; speedup vs baseline: 4.0813x; 1.0278x over previous
//
#include <hip/hip_runtime.h>
#include <math.h>

#define B_ 4
#define S_ 16
#define N_ 32
#define C_ 512
#define D_ 10
#define DD_ 100
#define ATT_IN_ 312
#define ATT_H_ 512
#define ATT_DIM_ 514
#define CX_ 514

typedef __attribute__((ext_vector_type(8))) _Float16 half8;
typedef __attribute__((ext_vector_type(4))) _Float16 half4v;
typedef __attribute__((ext_vector_type(4))) float floatx4;

// LDS frag-block swizzle (verified: bank conflicts -> 0 in round 8).
__device__ __forceinline__ int SWZ(int la, int ks) { return la ^ (la >> 3) ^ (ks & 7); }

// ---------------- Fused att chain: att(128x312) -> a(512) -> att_f(514) -> ha(256)
__global__ __launch_bounds__(512) void k_att(
    const float* __restrict__ att, const float* __restrict__ attW1,
    const float* __restrict__ attb1, const float* __restrict__ attW2,
    const float* __restrict__ attb2, const float* __restrict__ gW1,
    float* __restrict__ ha) {
    __shared__ float in_row[ATT_IN_];
    __shared__ float arow[512];
    __shared__ float frow[ATT_DIM_];
    __shared__ float Pc[512];
    int r = blockIdx.x;            // 0..127
    int tid = threadIdx.x;         // 0..511

    if (tid < ATT_IN_) in_row[tid] = att[r * ATT_IN_ + tid];
    __syncthreads();

#define LD8(buf, Wp, stride, g) { _Pragma("unroll") \
    for (int u = 0; u < 8; u++) buf[u] = Wp[((g) * 8 + u) * (stride)]; }
#define FM8(buf, src, acc, g) { _Pragma("unroll") \
    for (int u = 0; u < 8; u++) acc = fmaf(src[(g) * 8 + u], buf[u], acc); }

    // ---- phase A: arow[tid] = relu(in_row @ attW1 + b1) ; K=312=39x8
    {
        const float* Wp = attW1 + tid;
        float acc = attb1[tid];
        float wA[8], wB[8];
        LD8(wA, Wp, 512, 0);
#pragma unroll
        for (int g = 0; g < 36; g += 2) {
            LD8(wB, Wp, 512, g + 1); FM8(wA, in_row, acc, g);
            LD8(wA, Wp, 512, g + 2); FM8(wB, in_row, acc, g + 1);
        }
        LD8(wB, Wp, 512, 37); FM8(wA, in_row, acc, 36); FM8(wB, in_row, acc, 37);
        LD8(wA, Wp, 512, 38); FM8(wA, in_row, acc, 38);
        arow[tid] = fmaxf(acc, 0.f);
    }
    __syncthreads();

    // ---- phase B: frow[o] = relu(arow @ attW2 + b2) ; K=512=64x8
    {
        const float* Wp = attW2 + tid;
        float acc = attb2[tid];
        float wA[8], wB[8];
        LD8(wA, Wp, 514, 0);
#pragma unroll
        for (int g = 0; g < 62; g += 2) {
            LD8(wB, Wp, 514, g + 1); FM8(wA, arow, acc, g);
            LD8(wA, Wp, 514, g + 2); FM8(wB, arow, acc, g + 1);
        }
        LD8(wB, Wp, 514, 63); FM8(wA, arow, acc, 62); FM8(wB, arow, acc, 63);
        frow[tid] = fmaxf(acc, 0.f);
    }
    // ragged cols 512,513
    if (tid < 128) {
        int w = tid >> 6, lane = tid & 63;
        const float* Wc = attW2 + 512 + w;
        float p = 0.f;
#pragma unroll
        for (int m = 0; m < 8; m++) {
            int k = lane + m * 64;
            p = fmaf(arow[k], Wc[k * 514], p);
        }
#pragma unroll
        for (int off = 32; off; off >>= 1) p += __shfl_xor(p, off);
        if (lane == 0) frow[512 + w] = fmaxf(p + attb2[512 + w], 0.f);
    }
    __syncthreads();

    // ---- phase C: ha[o] = frow @ gW1[CX_:] ; K=514, split-K by 2
    {
        int o = tid & 255, h = tid >> 8;
        const float* Wp = gW1 + (size_t)(CX_ + h * 256) * 256 + o;
        const float* fr = frow + h * 256;
        float acc = 0.f;
        float wA[8], wB[8];
        LD8(wA, Wp, 256, 0);
#pragma unroll
        for (int g = 0; g < 30; g += 2) {
            LD8(wB, Wp, 256, g + 1); FM8(wA, fr, acc, g);
            LD8(wA, Wp, 256, g + 2); FM8(wB, fr, acc, g + 1);
        }
        LD8(wB, Wp, 256, 31); FM8(wA, fr, acc, 30); FM8(wB, fr, acc, 31);
        if (h == 1) {
            acc = fmaf(fr[256], Wp[256 * 256], acc);
            acc = fmaf(fr[257], Wp[257 * 256], acc);
        }
        Pc[tid] = acc;
    }
    __syncthreads();
    if (tid < 256) ha[r * 256 + tid] = Pc[tid] + Pc[tid + 256];
#undef LD8
#undef FM8
}

// ---------------- W prep: gW2/3/4 (->Wf) and gW1[:512] (->Wxf) as fp16 frag-linear.
__global__ void k_wprep(const float* __restrict__ gW1, const float* __restrict__ gW2,
                        const float* __restrict__ gW3, const float* __restrict__ gW4,
                        _Float16* __restrict__ Wf, _Float16* __restrict__ Wxf) {
    int f = blockIdx.x * 256 + threadIdx.x;        // 3*65536 (Wf) + 131072 (Wxf)
    if (f < 196608) {
        int j = f & 7, lane = (f >> 3) & 63, ct = (f >> 9) & 15, ks = (f >> 13) & 7, L = f >> 16;
        const float* W = (L == 0) ? gW2 : (L == 1) ? gW3 : gW4;
        int k = ks * 32 + ((lane >> 4) << 3) + j;
        int col = ct * 16 + (lane & 15);
        Wf[f] = (_Float16)W[k * 256 + col];
    } else {
        int g = f - 196608;
        int j = g & 7, lane = (g >> 3) & 63, ct = (g >> 9) & 15, ks = (g >> 13) & 15;
        int k = ks * 32 + ((lane >> 4) << 3) + j;
        int col = ct * 16 + (lane & 15);
        Wxf[g] = (_Float16)gW1[k * 256 + col];
    }
}

// ---------------- K4 (MFMA): hx16[g][c] = fp16( sum_k xf16[g,k]*Wx[k,c] + coord )
__global__ __launch_bounds__(256) void k_hx(const float* __restrict__ x_f,
                                            const float* __restrict__ gW1,
                                            const _Float16* __restrict__ Wxf,
                                            _Float16* __restrict__ hx16) {
    __shared__ _Float16 Ax[2][2048];
    int R0 = blockIdx.x * 64;
    int tid = threadIdx.x;
    int l = tid & 63, wc = tid >> 6;
    int c_loc = tid >> 3;
    int r0s = (tid & 7) * 8;
    int sbase[8];
    int srow_la[8], srow_rt[8];
#pragma unroll
    for (int u = 0; u < 8; u++) {
        int g = R0 + r0s + u;
        int bs = g / 100, p = g - bs * 100;
        sbase[u] = bs * 51200 + p;
        int row = r0s + u;
        srow_rt[u] = row >> 4;
        srow_la[u] = (row & 15) | (((c_loc >> 3) & 3) << 4);
    }
    int sj = c_loc & 7;

    {
        float xv[8];
#pragma unroll
        for (int u = 0; u < 8; u++) xv[u] = x_f[sbase[u] + c_loc * 100];
#pragma unroll
        for (int u = 0; u < 8; u++)
            Ax[0][srow_rt[u] * 512 + SWZ(srow_la[u], 0) * 8 + sj] = (_Float16)xv[u];
    }
    __syncthreads();

    floatx4 acc[4][4];
#pragma unroll
    for (int ti = 0; ti < 4; ti++)
#pragma unroll
        for (int tj = 0; tj < 4; tj++) acc[ti][tj] = (floatx4){0.f, 0.f, 0.f, 0.f};

    for (int ks = 0; ks < 16; ks++) {
        int cur = ks & 1;
        float xv[8];
        if (ks < 15) {
            int k1 = (ks + 1) * 32 + c_loc;
#pragma unroll
            for (int u = 0; u < 8; u++) xv[u] = x_f[sbase[u] + k1 * 100];
        }
#pragma unroll
        for (int ti = 0; ti < 4; ti++) {
            half8 afrag = *(const half8*)&Ax[cur][ti * 512 + SWZ(l, ks) * 8];
#pragma unroll
            for (int tj = 0; tj < 4; tj++) {
                int ct = wc * 4 + tj;
                half8 bfrag = *(const half8*)(Wxf + (size_t)((ks * 16 + ct) * 64 + l) * 8);
                acc[ti][tj] = __builtin_amdgcn_mfma_f32_16x16x32_f16(afrag, bfrag, acc[ti][tj], 0, 0, 0);
            }
        }
        if (ks < 15) {
#pragma unroll
            for (int u = 0; u < 8; u++)
                Ax[cur ^ 1][srow_rt[u] * 512 + SWZ(srow_la[u], ks + 1) * 8 + sj] = (_Float16)xv[u];
        }
        __syncthreads();
    }

    // epilogue: + coord channels, store fp16
#pragma unroll
    for (int tj = 0; tj < 4; tj++) {
        int col = wc * 64 + tj * 16 + (l & 15);
        float w512 = gW1[512 * 256 + col];
        float w513 = gW1[513 * 256 + col];
#pragma unroll
        for (int ti = 0; ti < 4; ti++) {
#pragma unroll
            for (int r = 0; r < 4; r++) {
                int g = R0 + ti * 16 + (l >> 4) * 4 + r;
                int bs = g / 100, p = g - bs * 100;
                float ci = (float)(p / 10) * 0.1f;
                float cj = (float)(p % 10) * 0.1f;
                hx16[((size_t)(bs * 100 + p) << 8) + col] =
                    (_Float16)(acc[ti][tj][r] + ci * w512 + cj * w513);
            }
        }
    }
}

// ---------------- Main (fp16 MFMA): h0=relu(hx+ha+gb1) -> 3 layers -> p-sum partials
// XCD-aware swizzle: XCD x (= bid&7) owns bs in [8x, 8x+8) -> hx16 slice 400 KB,
// Wf 384 KB, ha <=64 KB all L2-resident per XCD. No global atomics: block partials
// go to hpart16[(bs*50+blk)][seg][c] (unique writer per element), gathered by k_head.
__global__ __launch_bounds__(256, 4) void k_main(
    const _Float16* __restrict__ hx16, const float* __restrict__ ha,
    const float* __restrict__ gb1, const _Float16* __restrict__ Wf,
    const float* __restrict__ gb2, const float* __restrict__ gb3,
    const float* __restrict__ gb4, _Float16* __restrict__ hpart16) {
    __shared__ _Float16 As16[16384];               // 32 KB, frag-linear (swizzled)
    __shared__ float Pf[512];
    int bid = blockIdx.x;
    int x = bid & 7, j = bid >> 3;
    int bs = x * 8 + j / 50;
    int blk = j - (j / 50) * 50;
    int R0 = blk * 64;
    int b = bs >> 4;
    int tid = threadIdx.x;
    int l = tid & 63;
    int wc = tid >> 6;

    // ---- stage h0 = relu(hx16 + ha + gb1) -> fp16 frag-layout LDS ----
    {
        int i = tid >> 2, q4 = tid & 3;
        int rl = R0 + i;
        int n = rl / 100, p = rl - n * 100;
        const half8* xr = (const half8*)(hx16 + ((size_t)(bs * 100 + p) << 8) + q4 * 64);
        const float4* ar = (const float4*)(ha + ((size_t)(b * N_ + n) << 8) + q4 * 64);
        const float4* br = (const float4*)(gb1 + q4 * 64);
        int rt = i >> 4;
        int la_lo = i & 15;
#pragma unroll
        for (int c8 = 0; c8 < 8; c8++) {
            half8 xv = xr[c8];
            float4 a0 = ar[2 * c8], a1 = ar[2 * c8 + 1];
            float4 b0 = br[2 * c8], b1 = br[2 * c8 + 1];
            half8 hv;
            hv[0] = (_Float16)fmaxf((float)xv[0] + a0.x + b0.x, 0.f);
            hv[1] = (_Float16)fmaxf((float)xv[1] + a0.y + b0.y, 0.f);
            hv[2] = (_Float16)fmaxf((float)xv[2] + a0.z + b0.z, 0.f);
            hv[3] = (_Float16)fmaxf((float)xv[3] + a0.w + b0.w, 0.f);
            hv[4] = (_Float16)fmaxf((float)xv[4] + a1.x + b1.x, 0.f);
            hv[5] = (_Float16)fmaxf((float)xv[5] + a1.y + b1.y, 0.f);
            hv[6] = (_Float16)fmaxf((float)xv[6] + a1.z + b1.z, 0.f);
            hv[7] = (_Float16)fmaxf((float)xv[7] + a1.w + b1.w, 0.f);
            int k0 = q4 * 64 + c8 * 8;
            int ks = k0 >> 5;
            int la = la_lo | (((k0 >> 3) & 3) << 4);
            *(half8*)&As16[((ks * 4 + rt) << 9) + SWZ(la, ks) * 8] = hv;
        }
    }
    __syncthreads();

    const float* biases[3] = {gb2, gb3, gb4};
    floatx4 acc[4][4];
    for (int layer = 0; layer < 3; layer++) {
#pragma unroll
        for (int ti = 0; ti < 4; ti++)
#pragma unroll
            for (int tj = 0; tj < 4; tj++) acc[ti][tj] = (floatx4){0.f, 0.f, 0.f, 0.f};

        const _Float16* WfL = Wf + layer * 65536;
        half8 bcur[4], bnxt[4];
#pragma unroll
        for (int tj = 0; tj < 4; tj++)
            bcur[tj] = *(const half8*)(WfL + (size_t)((0 * 16 + wc * 4 + tj) * 64 + l) * 8);
#pragma unroll
        for (int ks = 0; ks < 8; ks++) {
            if (ks < 7) {
#pragma unroll
                for (int tj = 0; tj < 4; tj++)
                    bnxt[tj] = *(const half8*)(WfL + (size_t)(((ks + 1) * 16 + wc * 4 + tj) * 64 + l) * 8);
            }
#pragma unroll
            for (int ti = 0; ti < 4; ti++) {
                half8 afrag = *(const half8*)&As16[((ks * 4 + ti) << 9) + SWZ(l, ks) * 8];
#pragma unroll
                for (int tj = 0; tj < 4; tj++)
                    acc[ti][tj] = __builtin_amdgcn_mfma_f32_16x16x32_f16(afrag, bcur[tj], acc[ti][tj], 0, 0, 0);
            }
#pragma unroll
            for (int tj = 0; tj < 4; tj++) bcur[tj] = bnxt[tj];
        }
        __syncthreads();

        if (layer < 2) {
            const float* bias = biases[layer];
#pragma unroll
            for (int tj = 0; tj < 4; tj++) {
                int col = wc * 64 + tj * 16 + (l & 15);
                float bv = bias[col];
                int ksp = col >> 5;
                int lane_hi = ((col >> 3) & 3) << 4;
                int jj = col & 7;
#pragma unroll
                for (int ti = 0; ti < 4; ti++) {
#pragma unroll
                    for (int r = 0; r < 4; r++) {
                        float v = fmaxf(acc[ti][tj][r] + bv, 0.f);
                        int la = ((l >> 4) * 4 + r) | lane_hi;
                        As16[((ksp * 4 + ti) << 9) + SWZ(la, ksp) * 8 + jj] = (_Float16)v;
                    }
                }
            }
            __syncthreads();
        } else {
            // relu + p-sum partials (<=2 n-segments); unique writer per Pf element
            int n0 = R0 / 100;
            int bound = (n0 + 1) * 100;
            const float* bias = biases[2];
#pragma unroll
            for (int tj = 0; tj < 4; tj++) {
                int col = wc * 64 + tj * 16 + (l & 15);
                float bv = bias[col];
                float p0 = 0.f, p1 = 0.f;
#pragma unroll
                for (int ti = 0; ti < 4; ti++) {
#pragma unroll
                    for (int r = 0; r < 4; r++) {
                        int rl = R0 + ti * 16 + (l >> 4) * 4 + r;
                        float v = fmaxf(acc[ti][tj][r] + bv, 0.f);
                        bool in1 = rl >= bound;
                        p0 += in1 ? 0.f : v;
                        p1 += in1 ? v : 0.f;
                    }
                }
                p0 += __shfl_xor(p0, 16); p0 += __shfl_xor(p0, 32);
                p1 += __shfl_xor(p1, 16); p1 += __shfl_xor(p1, 32);
                if (l < 16) {
                    Pf[col] = p0;
                    Pf[256 + col] = p1;
                }
            }
            __syncthreads();
            if (tid < 64) {            // 64 thr x half4v = 256 cols per segment
                half4v h0v, h1v;
#pragma unroll
                for (int e = 0; e < 4; e++) {
                    h0v[e] = (_Float16)Pf[tid * 4 + e];
                    h1v[e] = (_Float16)Pf[256 + tid * 4 + e];
                }
                _Float16* hp = hpart16 + (((size_t)bs * 50 + blk) << 9);
                *(half4v*)&hp[tid * 4] = h0v;
                *(half4v*)&hp[256 + tid * 4] = h1v;
            }
        }
    }
}

// ---------------- Head: gather hpart16 -> f1 -> f2 -> y(29) -> BN -> relu -> loss
__global__ void k_head(const _Float16* __restrict__ hpart16,
                       const float* __restrict__ fW1, const float* __restrict__ fb1,
                       const float* __restrict__ fW2, const float* __restrict__ fb2,
                       const float* __restrict__ fW3, const float* __restrict__ fb3,
                       const float* __restrict__ bn_gamma, const float* __restrict__ bn_beta,
                       const float* __restrict__ bn_mean, const float* __restrict__ bn_var,
                       const float* __restrict__ fW4, const float* __restrict__ fb4,
                       const int* __restrict__ x_label, const int* __restrict__ att_label,
                       float* __restrict__ out) {
    __shared__ float H[8 * 256];
    __shared__ float Y[8 * 29];
    __shared__ float partial[8];
    int RB = blockIdx.x * 8;       // 8 rows (bs,n): bs = RB>>5, n = (RB&31)+r
    int tid = threadIdx.x;
    {
        int bs = RB >> 5;
        int nb = RB & 31;
        int c = tid;               // 0..255
#pragma unroll
        for (int r = 0; r < 8; r++) {
            int n = nb + r;
            int blo = (n == 0) ? 0 : (100 * (n - 1)) >> 6;
            int bhi = (100 * (n + 1) + 63) >> 6;
            if (bhi > 49) bhi = 49;
            float acc = 0.f;
            for (int blk = blo; blk <= bhi; blk++) {
                int n0 = (blk << 6) / 100;
                const _Float16* hp = hpart16 + (((size_t)bs * 50 + blk) << 9);
                if (n0 == n) acc += (float)hp[c];
                else if (n0 == n - 1) acc += (float)hp[256 + c];
            }
            H[r * 256 + c] = acc;
        }
    }
    __syncthreads();
    const float* Ws[2] = {fW1, fW2};
    const float* Bs[2] = {fb1, fb2};
#pragma unroll
    for (int layer = 0; layer < 2; layer++) {
        float acc[8];
#pragma unroll
        for (int r = 0; r < 8; r++) acc[r] = Bs[layer][tid];
        const float* W = Ws[layer];
#pragma unroll 16
        for (int k = 0; k < 256; k++) {
            float w = W[k * 256 + tid];
#pragma unroll
            for (int r = 0; r < 8; r++) acc[r] = fmaf(H[r * 256 + k], w, acc[r]);
        }
        __syncthreads();
#pragma unroll
        for (int r = 0; r < 8; r++) H[r * 256 + tid] = fmaxf(acc[r], 0.f);
        __syncthreads();
    }
    if (tid < 8 * 29) {
        int r = tid / 29, c = tid % 29;
        float acc = fb3[c];
#pragma unroll 8
        for (int k = 0; k < 256; k++) acc = fmaf(H[r * 256 + k], fW3[k * 29 + c], acc);
        float v = (acc - bn_mean[c]) * rsqrtf(bn_var[c] + 1e-5f) * bn_gamma[c] + bn_beta[c];
        Y[r * 29 + c] = fmaxf(v, 0.f);
    }
    __syncthreads();
    if (tid < 8) {
        int r = tid;
        float s = fb4[0];
#pragma unroll
        for (int c = 0; c < 29; c++) s = fmaf(Y[r * 29 + c], fW4[c], s);
        float score = 1.f / (1.f + expf(-s));
        int g = RB + r;
        int b = g >> 9;
        int rem = g & 511;
        int si = rem >> 5, n = rem & 31;
        float label = (x_label[b * S_ + si] == att_label[b * N_ + n]) ? 1.f : 0.f;
        float d = label - score;
        partial[r] = d * d;
    }
    __syncthreads();
    if (tid == 0) {
        float s = 0.f;
#pragma unroll
        for (int r = 0; r < 8; r++) s += partial[r];
        atomicAdd(out, s);
    }
}

extern "C" void kernel_launch(void* const* d_in, const int* in_sizes, int n_in,
                              void* d_out, int out_size, void* d_ws, size_t ws_size,
                              hipStream_t stream) {
    const float* x_f      = (const float*)d_in[0];
    const float* att      = (const float*)d_in[1];
    const int*   x_label  = (const int*)d_in[2];
    const int*   att_label= (const int*)d_in[3];
    const float* attW1    = (const float*)d_in[4];
    const float* attb1    = (const float*)d_in[5];
    const float* attW2    = (const float*)d_in[6];
    const float* attb2    = (const float*)d_in[7];
    const float* gW1      = (const float*)d_in[8];
    const float* gb1      = (const float*)d_in[9];
    const float* gW2      = (const float*)d_in[10];
    const float* gb2      = (const float*)d_in[11];
    const float* gW3      = (const float*)d_in[12];
    const float* gb3      = (const float*)d_in[13];
    const float* gW4      = (const float*)d_in[14];
    const float* gb4      = (const float*)d_in[15];
    const float* fW1      = (const float*)d_in[16];
    const float* fb1      = (const float*)d_in[17];
    const float* fW2      = (const float*)d_in[18];
    const float* fb2      = (const float*)d_in[19];
    const float* fW3      = (const float*)d_in[20];
    const float* fb3      = (const float*)d_in[21];
    const float* bn_gamma = (const float*)d_in[22];
    const float* bn_beta  = (const float*)d_in[23];
    const float* bn_mean  = (const float*)d_in[24];
    const float* bn_var   = (const float*)d_in[25];
    const float* fW4      = (const float*)d_in[26];
    const float* fb4      = (const float*)d_in[27];

    float* ws = (float*)d_ws;
    _Float16* hx16    = (_Float16*)ws;                    // 1,638,400 halves = 819200 f
    float*    ha      = ws + 819200;                      // 32768 f
    _Float16* hpart16 = (_Float16*)(ws + 851968);         // 1,638,400 halves = 819200 f
    _Float16* Wf      = (_Float16*)(ws + 1671168);        // 196608 halves = 98304 f
    _Float16* Wxf     = (_Float16*)(ws + 1769472);        // 131072 halves = 65536 f
    // total ws: 1,835,008 floats = 7.34 MB

    hipMemsetAsync(d_out, 0, sizeof(float), stream);

    k_att<<<128, 512, 0, stream>>>(att, attW1, attb1, attW2, attb2, gW1, ha);
    k_wprep<<<1280, 256, 0, stream>>>(gW1, gW2, gW3, gW4, Wf, Wxf);
    k_hx<<<100, 256, 0, stream>>>(x_f, gW1, Wxf, hx16);
    k_main<<<3200, 256, 0, stream>>>(hx16, ha, gb1, Wf, gb2, gb3, gb4, hpart16);
    k_head<<<256, 256, 0, stream>>>(hpart16, fW1, fb1, fW2, fb2, fW3, fb3,
                                    bn_gamma, bn_beta, bn_mean, bn_var,
                                    fW4, fb4, x_label, att_label, (float*)d_out);
}

// Round 11
// 328.755 us; speedup vs baseline: 4.4770x; 1.0970x over previous
//
#include <hip/hip_runtime.h>
#include <math.h>

#define B_ 4
#define S_ 16
#define N_ 32
#define C_ 512
#define D_ 10
#define DD_ 100
#define ATT_IN_ 312
#define ATT_H_ 512
#define ATT_DIM_ 514
#define CX_ 514

typedef __attribute__((ext_vector_type(8))) _Float16 half8;
typedef __attribute__((ext_vector_type(4))) _Float16 half4v;
typedef __attribute__((ext_vector_type(4))) float floatx4;

// LDS frag-block swizzle (verified: bank conflicts -> 0 in round 8).
__device__ __forceinline__ int SWZ(int la, int ks) { return la ^ (la >> 3) ^ (ks & 7); }

// 2-deep software-pipelined GEMV ladder: G groups of 8 k-steps, column-strided W.
template<int G, int STRIDE>
__device__ __forceinline__ float gemv_pipe(const float* __restrict__ Wp,
                                           const float* __restrict__ src) {
    float wA[8], wB[8];
    float acc = 0.f;
#define LD8_(buf, g) { _Pragma("unroll") \
    for (int u = 0; u < 8; u++) buf[u] = Wp[((g) * 8 + u) * STRIDE]; }
#define FM8_(buf, g) { _Pragma("unroll") \
    for (int u = 0; u < 8; u++) acc = fmaf(src[(g) * 8 + u], buf[u], acc); }
    LD8_(wA, 0);
#pragma unroll
    for (int g = 0; g + 2 < G; g += 2) {
        LD8_(wB, g + 1); FM8_(wA, g);
        LD8_(wA, g + 2); FM8_(wB, g + 1);
    }
    if constexpr ((G & 1) == 0) {
        LD8_(wB, G - 1); FM8_(wA, G - 2); FM8_(wB, G - 1);
    } else {
        FM8_(wA, G - 1);
    }
#undef LD8_
#undef FM8_
    return acc;
}

// ---------------- Fused att chain, 1024 thr: full split-K per phase.
// 128 blocks x 1024 thr (16 waves/CU on 128 CUs). Wave-uniform K-splits.
__global__ __launch_bounds__(1024) void k_att(
    const float* __restrict__ att, const float* __restrict__ attW1,
    const float* __restrict__ attb1, const float* __restrict__ attW2,
    const float* __restrict__ attb2, const float* __restrict__ gW1,
    float* __restrict__ ha) {
    __shared__ float in_row[ATT_IN_];
    __shared__ float arow[512];
    __shared__ float frow[ATT_DIM_];
    __shared__ float P[1024];
    int r = blockIdx.x;            // 0..127
    int tid = threadIdx.x;         // 0..1023

    if (tid < ATT_IN_) in_row[tid] = att[r * ATT_IN_ + tid];
    __syncthreads();

    // ---- phase A: arow = relu(in_row @ attW1 + b1); K=312 split 160/152
    {
        int o = tid & 511, h = tid >> 9;
        float acc = (h == 0) ? gemv_pipe<20, 512>(attW1 + o, in_row)
                             : gemv_pipe<19, 512>(attW1 + 160 * 512 + o, in_row + 160);
        P[tid] = acc;
    }
    __syncthreads();
    if (tid < 512) arow[tid] = fmaxf(P[tid] + P[tid + 512] + attb1[tid], 0.f);
    __syncthreads();

    // ---- phase B: frow = relu(arow @ attW2 + b2); K=512 split 256/256
    {
        int o = tid & 511, h = tid >> 9;
        P[tid] = gemv_pipe<32, 514>(attW2 + h * 256 * 514 + o, arow + h * 256);
    }
    __syncthreads();
    if (tid < 512) {
        frow[tid] = fmaxf(P[tid] + P[tid + 512] + attb2[tid], 0.f);
    } else if (tid < 640) {        // ragged cols 512,513: one wave each
        int w = (tid >> 6) & 1, lane = tid & 63;
        const float* Wc = attW2 + 512 + w;
        float p = 0.f;
#pragma unroll
        for (int m = 0; m < 8; m++) {
            int k = lane + m * 64;
            p = fmaf(arow[k], Wc[k * 514], p);
        }
#pragma unroll
        for (int off = 32; off; off >>= 1) p += __shfl_xor(p, off);
        if (lane == 0) frow[512 + w] = fmaxf(p + attb2[512 + w], 0.f);
    }
    __syncthreads();

    // ---- phase C: ha = frow @ gW1[CX_:]; K=514 split 128/128/128/130
    {
        int o = tid & 255, q = tid >> 8;
        const float* Wp = gW1 + (size_t)(CX_ + q * 128) * 256 + o;
        const float* fr = frow + q * 128;
        float acc = gemv_pipe<16, 256>(Wp, fr);
        if (q == 3) {              // tail k = 512, 513
            acc = fmaf(fr[128], Wp[128 * 256], acc);
            acc = fmaf(fr[129], Wp[129 * 256], acc);
        }
        P[tid] = acc;
    }
    __syncthreads();
    if (tid < 256) ha[r * 256 + tid] = P[tid] + P[tid + 256] + P[tid + 512] + P[tid + 768];
}

// ---------------- W prep: gW2/3/4 (->Wf) and gW1[:512] (->Wxf) as fp16 frag-linear.
__global__ void k_wprep(const float* __restrict__ gW1, const float* __restrict__ gW2,
                        const float* __restrict__ gW3, const float* __restrict__ gW4,
                        _Float16* __restrict__ Wf, _Float16* __restrict__ Wxf) {
    int f = blockIdx.x * 256 + threadIdx.x;        // 3*65536 (Wf) + 131072 (Wxf)
    if (f < 196608) {
        int j = f & 7, lane = (f >> 3) & 63, ct = (f >> 9) & 15, ks = (f >> 13) & 7, L = f >> 16;
        const float* W = (L == 0) ? gW2 : (L == 1) ? gW3 : gW4;
        int k = ks * 32 + ((lane >> 4) << 3) + j;
        int col = ct * 16 + (lane & 15);
        Wf[f] = (_Float16)W[k * 256 + col];
    } else {
        int g = f - 196608;
        int j = g & 7, lane = (g >> 3) & 63, ct = (g >> 9) & 15, ks = (g >> 13) & 15;
        int k = ks * 32 + ((lane >> 4) << 3) + j;
        int col = ct * 16 + (lane & 15);
        Wxf[g] = (_Float16)gW1[k * 256 + col];
    }
}

// ---------------- K4 (MFMA): hx16[g][c] = fp16( sum_k xf16[g,k]*Wx[k,c] + coord )
__global__ __launch_bounds__(256) void k_hx(const float* __restrict__ x_f,
                                            const float* __restrict__ gW1,
                                            const _Float16* __restrict__ Wxf,
                                            _Float16* __restrict__ hx16) {
    __shared__ _Float16 Ax[2][2048];
    int R0 = blockIdx.x * 64;
    int tid = threadIdx.x;
    int l = tid & 63, wc = tid >> 6;
    int c_loc = tid >> 3;
    int r0s = (tid & 7) * 8;
    int sbase[8];
    int srow_la[8], srow_rt[8];
#pragma unroll
    for (int u = 0; u < 8; u++) {
        int g = R0 + r0s + u;
        int bs = g / 100, p = g - bs * 100;
        sbase[u] = bs * 51200 + p;
        int row = r0s + u;
        srow_rt[u] = row >> 4;
        srow_la[u] = (row & 15) | (((c_loc >> 3) & 3) << 4);
    }
    int sj = c_loc & 7;

    {
        float xv[8];
#pragma unroll
        for (int u = 0; u < 8; u++) xv[u] = x_f[sbase[u] + c_loc * 100];
#pragma unroll
        for (int u = 0; u < 8; u++)
            Ax[0][srow_rt[u] * 512 + SWZ(srow_la[u], 0) * 8 + sj] = (_Float16)xv[u];
    }
    __syncthreads();

    floatx4 acc[4][4];
#pragma unroll
    for (int ti = 0; ti < 4; ti++)
#pragma unroll
        for (int tj = 0; tj < 4; tj++) acc[ti][tj] = (floatx4){0.f, 0.f, 0.f, 0.f};

    for (int ks = 0; ks < 16; ks++) {
        int cur = ks & 1;
        float xv[8];
        if (ks < 15) {
            int k1 = (ks + 1) * 32 + c_loc;
#pragma unroll
            for (int u = 0; u < 8; u++) xv[u] = x_f[sbase[u] + k1 * 100];
        }
#pragma unroll
        for (int ti = 0; ti < 4; ti++) {
            half8 afrag = *(const half8*)&Ax[cur][ti * 512 + SWZ(l, ks) * 8];
#pragma unroll
            for (int tj = 0; tj < 4; tj++) {
                int ct = wc * 4 + tj;
                half8 bfrag = *(const half8*)(Wxf + (size_t)((ks * 16 + ct) * 64 + l) * 8);
                acc[ti][tj] = __builtin_amdgcn_mfma_f32_16x16x32_f16(afrag, bfrag, acc[ti][tj], 0, 0, 0);
            }
        }
        if (ks < 15) {
#pragma unroll
            for (int u = 0; u < 8; u++)
                Ax[cur ^ 1][srow_rt[u] * 512 + SWZ(srow_la[u], ks + 1) * 8 + sj] = (_Float16)xv[u];
        }
        __syncthreads();
    }

    // epilogue: + coord channels, store fp16
#pragma unroll
    for (int tj = 0; tj < 4; tj++) {
        int col = wc * 64 + tj * 16 + (l & 15);
        float w512 = gW1[512 * 256 + col];
        float w513 = gW1[513 * 256 + col];
#pragma unroll
        for (int ti = 0; ti < 4; ti++) {
#pragma unroll
            for (int r = 0; r < 4; r++) {
                int g = R0 + ti * 16 + (l >> 4) * 4 + r;
                int bs = g / 100, p = g - bs * 100;
                float ci = (float)(p / 10) * 0.1f;
                float cj = (float)(p % 10) * 0.1f;
                hx16[((size_t)(bs * 100 + p) << 8) + col] =
                    (_Float16)(acc[ti][tj][r] + ci * w512 + cj * w513);
            }
        }
    }
}

// ---------------- Main (fp16 MFMA): h0=relu(hx+ha+gb1) -> 3 layers -> p-sum partials
// Round-6-proven inner loop (direct bfrag loads, no prefetch regs) + (256,3):
// removes the suspected register-overflow scratch traffic of rounds 8/10.
// Keeps: SWZ (0 conflicts), hx16 fp16, XCD-aware bs partition, atomic-free hpart16.
__global__ __launch_bounds__(256, 3) void k_main(
    const _Float16* __restrict__ hx16, const float* __restrict__ ha,
    const float* __restrict__ gb1, const _Float16* __restrict__ Wf,
    const float* __restrict__ gb2, const float* __restrict__ gb3,
    const float* __restrict__ gb4, _Float16* __restrict__ hpart16) {
    __shared__ _Float16 As16[16384];               // 32 KB, frag-linear (swizzled)
    __shared__ float Pf[512];
    int bid = blockIdx.x;
    int x = bid & 7, j = bid >> 3;
    int bs = x * 8 + j / 50;
    int blk = j - (j / 50) * 50;
    int R0 = blk * 64;
    int b = bs >> 4;
    int tid = threadIdx.x;
    int l = tid & 63;
    int wc = tid >> 6;

    // ---- stage h0 = relu(hx16 + ha + gb1) -> fp16 frag-layout LDS ----
    {
        int i = tid >> 2, q4 = tid & 3;
        int rl = R0 + i;
        int n = rl / 100, p = rl - n * 100;
        const half8* xr = (const half8*)(hx16 + ((size_t)(bs * 100 + p) << 8) + q4 * 64);
        const float4* ar = (const float4*)(ha + ((size_t)(b * N_ + n) << 8) + q4 * 64);
        const float4* br = (const float4*)(gb1 + q4 * 64);
        int rt = i >> 4;
        int la_lo = i & 15;
#pragma unroll
        for (int c8 = 0; c8 < 8; c8++) {
            half8 xv = xr[c8];
            float4 a0 = ar[2 * c8], a1 = ar[2 * c8 + 1];
            float4 b0 = br[2 * c8], b1 = br[2 * c8 + 1];
            half8 hv;
            hv[0] = (_Float16)fmaxf((float)xv[0] + a0.x + b0.x, 0.f);
            hv[1] = (_Float16)fmaxf((float)xv[1] + a0.y + b0.y, 0.f);
            hv[2] = (_Float16)fmaxf((float)xv[2] + a0.z + b0.z, 0.f);
            hv[3] = (_Float16)fmaxf((float)xv[3] + a0.w + b0.w, 0.f);
            hv[4] = (_Float16)fmaxf((float)xv[4] + a1.x + b1.x, 0.f);
            hv[5] = (_Float16)fmaxf((float)xv[5] + a1.y + b1.y, 0.f);
            hv[6] = (_Float16)fmaxf((float)xv[6] + a1.z + b1.z, 0.f);
            hv[7] = (_Float16)fmaxf((float)xv[7] + a1.w + b1.w, 0.f);
            int k0 = q4 * 64 + c8 * 8;
            int ks = k0 >> 5;
            int la = la_lo | (((k0 >> 3) & 3) << 4);
            *(half8*)&As16[((ks * 4 + rt) << 9) + SWZ(la, ks) * 8] = hv;
        }
    }
    __syncthreads();

    const float* biases[3] = {gb2, gb3, gb4};
    floatx4 acc[4][4];
    for (int layer = 0; layer < 3; layer++) {
#pragma unroll
        for (int ti = 0; ti < 4; ti++)
#pragma unroll
            for (int tj = 0; tj < 4; tj++) acc[ti][tj] = (floatx4){0.f, 0.f, 0.f, 0.f};

        const _Float16* WfL = Wf + layer * 65536;
#pragma unroll 2
        for (int ks = 0; ks < 8; ks++) {
            half8 afrag[4];
#pragma unroll
            for (int ti = 0; ti < 4; ti++)
                afrag[ti] = *(const half8*)&As16[((ks * 4 + ti) << 9) + SWZ(l, ks) * 8];
#pragma unroll
            for (int tj = 0; tj < 4; tj++) {
                half8 bfrag = *(const half8*)(WfL + (size_t)((ks * 16 + wc * 4 + tj) * 64 + l) * 8);
#pragma unroll
                for (int ti = 0; ti < 4; ti++)
                    acc[ti][tj] = __builtin_amdgcn_mfma_f32_16x16x32_f16(afrag[ti], bfrag, acc[ti][tj], 0, 0, 0);
            }
        }
        __syncthreads();

        if (layer < 2) {
            const float* bias = biases[layer];
#pragma unroll
            for (int tj = 0; tj < 4; tj++) {
                int col = wc * 64 + tj * 16 + (l & 15);
                float bv = bias[col];
                int ksp = col >> 5;
                int lane_hi = ((col >> 3) & 3) << 4;
                int jj = col & 7;
#pragma unroll
                for (int ti = 0; ti < 4; ti++) {
#pragma unroll
                    for (int r = 0; r < 4; r++) {
                        float v = fmaxf(acc[ti][tj][r] + bv, 0.f);
                        int la = ((l >> 4) * 4 + r) | lane_hi;
                        As16[((ksp * 4 + ti) << 9) + SWZ(la, ksp) * 8 + jj] = (_Float16)v;
                    }
                }
            }
            __syncthreads();
        } else {
            // relu + p-sum partials (<=2 n-segments); unique writer per Pf element
            int n0 = R0 / 100;
            int bound = (n0 + 1) * 100;
            const float* bias = biases[2];
#pragma unroll
            for (int tj = 0; tj < 4; tj++) {
                int col = wc * 64 + tj * 16 + (l & 15);
                float bv = bias[col];
                float p0 = 0.f, p1 = 0.f;
#pragma unroll
                for (int ti = 0; ti < 4; ti++) {
#pragma unroll
                    for (int r = 0; r < 4; r++) {
                        int rl = R0 + ti * 16 + (l >> 4) * 4 + r;
                        float v = fmaxf(acc[ti][tj][r] + bv, 0.f);
                        bool in1 = rl >= bound;
                        p0 += in1 ? 0.f : v;
                        p1 += in1 ? v : 0.f;
                    }
                }
                p0 += __shfl_xor(p0, 16); p0 += __shfl_xor(p0, 32);
                p1 += __shfl_xor(p1, 16); p1 += __shfl_xor(p1, 32);
                if (l < 16) {
                    Pf[col] = p0;
                    Pf[256 + col] = p1;
                }
            }
            __syncthreads();
            if (tid < 64) {            // 64 thr x half4v = 256 cols per segment
                half4v h0v, h1v;
#pragma unroll
                for (int e = 0; e < 4; e++) {
                    h0v[e] = (_Float16)Pf[tid * 4 + e];
                    h1v[e] = (_Float16)Pf[256 + tid * 4 + e];
                }
                _Float16* hp = hpart16 + (((size_t)bs * 50 + blk) << 9);
                *(half4v*)&hp[tid * 4] = h0v;
                *(half4v*)&hp[256 + tid * 4] = h1v;
            }
        }
    }
}

// ---------------- Head: gather hpart16 -> f1 -> f2 -> y(29) -> BN -> relu -> loss
__global__ void k_head(const _Float16* __restrict__ hpart16,
                       const float* __restrict__ fW1, const float* __restrict__ fb1,
                       const float* __restrict__ fW2, const float* __restrict__ fb2,
                       const float* __restrict__ fW3, const float* __restrict__ fb3,
                       const float* __restrict__ bn_gamma, const float* __restrict__ bn_beta,
                       const float* __restrict__ bn_mean, const float* __restrict__ bn_var,
                       const float* __restrict__ fW4, const float* __restrict__ fb4,
                       const int* __restrict__ x_label, const int* __restrict__ att_label,
                       float* __restrict__ out) {
    __shared__ float H[8 * 256];
    __shared__ float Y[8 * 29];
    __shared__ float partial[8];
    int RB = blockIdx.x * 8;       // 8 rows (bs,n): bs = RB>>5, n = (RB&31)+r
    int tid = threadIdx.x;
    {
        int bs = RB >> 5;
        int nb = RB & 31;
        int c = tid;               // 0..255
#pragma unroll
        for (int r = 0; r < 8; r++) {
            int n = nb + r;
            int blo = (n == 0) ? 0 : (100 * (n - 1)) >> 6;
            int bhi = (100 * (n + 1) + 63) >> 6;
            if (bhi > 49) bhi = 49;
            float acc = 0.f;
            for (int blk = blo; blk <= bhi; blk++) {
                int n0 = (blk << 6) / 100;
                const _Float16* hp = hpart16 + (((size_t)bs * 50 + blk) << 9);
                if (n0 == n) acc += (float)hp[c];
                else if (n0 == n - 1) acc += (float)hp[256 + c];
            }
            H[r * 256 + c] = acc;
        }
    }
    __syncthreads();
    const float* Ws[2] = {fW1, fW2};
    const float* Bs[2] = {fb1, fb2};
#pragma unroll
    for (int layer = 0; layer < 2; layer++) {
        float acc[8];
#pragma unroll
        for (int r = 0; r < 8; r++) acc[r] = Bs[layer][tid];
        const float* W = Ws[layer];
#pragma unroll 16
        for (int k = 0; k < 256; k++) {
            float w = W[k * 256 + tid];
#pragma unroll
            for (int r = 0; r < 8; r++) acc[r] = fmaf(H[r * 256 + k], w, acc[r]);
        }
        __syncthreads();
#pragma unroll
        for (int r = 0; r < 8; r++) H[r * 256 + tid] = fmaxf(acc[r], 0.f);
        __syncthreads();
    }
    if (tid < 8 * 29) {
        int r = tid / 29, c = tid % 29;
        float acc = fb3[c];
#pragma unroll 8
        for (int k = 0; k < 256; k++) acc = fmaf(H[r * 256 + k], fW3[k * 29 + c], acc);
        float v = (acc - bn_mean[c]) * rsqrtf(bn_var[c] + 1e-5f) * bn_gamma[c] + bn_beta[c];
        Y[r * 29 + c] = fmaxf(v, 0.f);
    }
    __syncthreads();
    if (tid < 8) {
        int r = tid;
        float s = fb4[0];
#pragma unroll
        for (int c = 0; c < 29; c++) s = fmaf(Y[r * 29 + c], fW4[c], s);
        float score = 1.f / (1.f + expf(-s));
        int g = RB + r;
        int b = g >> 9;
        int rem = g & 511;
        int si = rem >> 5, n = rem & 31;
        float label = (x_label[b * S_ + si] == att_label[b * N_ + n]) ? 1.f : 0.f;
        float d = label - score;
        partial[r] = d * d;
    }
    __syncthreads();
    if (tid == 0) {
        float s = 0.f;
#pragma unroll
        for (int r = 0; r < 8; r++) s += partial[r];
        atomicAdd(out, s);
    }
}

extern "C" void kernel_launch(void* const* d_in, const int* in_sizes, int n_in,
                              void* d_out, int out_size, void* d_ws, size_t ws_size,
                              hipStream_t stream) {
    const float* x_f      = (const float*)d_in[0];
    const float* att      = (const float*)d_in[1];
    const int*   x_label  = (const int*)d_in[2];
    const int*   att_label= (const int*)d_in[3];
    const float* attW1    = (const float*)d_in[4];
    const float* attb1    = (const float*)d_in[5];
    const float* attW2    = (const float*)d_in[6];
    const float* attb2    = (const float*)d_in[7];
    const float* gW1      = (const float*)d_in[8];
    const float* gb1      = (const float*)d_in[9];
    const float* gW2      = (const float*)d_in[10];
    const float* gb2      = (const float*)d_in[11];
    const float* gW3      = (const float*)d_in[12];
    const float* gb3      = (const float*)d_in[13];
    const float* gW4      = (const float*)d_in[14];
    const float* gb4      = (const float*)d_in[15];
    const float* fW1      = (const float*)d_in[16];
    const float* fb1      = (const float*)d_in[17];
    const float* fW2      = (const float*)d_in[18];
    const float* fb2      = (const float*)d_in[19];
    const float* fW3      = (const float*)d_in[20];
    const float* fb3      = (const float*)d_in[21];
    const float* bn_gamma = (const float*)d_in[22];
    const float* bn_beta  = (const float*)d_in[23];
    const float* bn_mean  = (const float*)d_in[24];
    const float* bn_var   = (const float*)d_in[25];
    const float* fW4      = (const float*)d_in[26];
    const float* fb4      = (const float*)d_in[27];

    float* ws = (float*)d_ws;
    _Float16* hx16    = (_Float16*)ws;                    // 1,638,400 halves = 819200 f
    float*    ha      = ws + 819200;                      // 32768 f
    _Float16* hpart16 = (_Float16*)(ws + 851968);         // 1,638,400 halves = 819200 f
    _Float16* Wf      = (_Float16*)(ws + 1671168);        // 196608 halves = 98304 f
    _Float16* Wxf     = (_Float16*)(ws + 1769472);        // 131072 halves = 65536 f
    // total ws: 1,835,008 floats = 7.34 MB

    hipMemsetAsync(d_out, 0, sizeof(float), stream);

    k_att<<<128, 1024, 0, stream>>>(att, attW1, attb1, attW2, attb2, gW1, ha);
    k_wprep<<<1280, 256, 0, stream>>>(gW1, gW2, gW3, gW4, Wf, Wxf);
    k_hx<<<100, 256, 0, stream>>>(x_f, gW1, Wxf, hx16);
    k_main<<<3200, 256, 0, stream>>>(hx16, ha, gb1, Wf, gb2, gb3, gb4, hpart16);
    k_head<<<256, 256, 0, stream>>>(hpart16, fW1, fb1, fW2, fb2, fW3, fb3,
                                    bn_gamma, bn_beta, bn_mean, bn_var,
                                    fW4, fb4, x_label, att_label, (float*)d_out);
}